// Round 1
// baseline (716.564 us; speedup 1.0000x reference)
//
#include <hip/hip_runtime.h>
#include <math.h>

namespace {

constexpr int Bc = 4;
constexpr int Cc = 256;
constexpr int Pc = 128;
constexpr int Nc = 3136;   // 56*56
constexpr int Sc = 5;
constexpr int KS = 14;     // split-K chunks for the ABT GEMM (3136 = 14*224)
constexpr float EPSc = 1e-5f;

// ---------------------------------------------------------------------------
// Generic f32 tiled GEMM: C[M,N] = epi( A[M,K] * B[K,N] (+ A2*B2 if DUAL) )
// N is always Nc (=3136 = 49*64), M and K multiples of 64/16.
// EPI: 0 = none, 1 = relu, 2 = multiply by 0.5*dinv[col]
// ---------------------------------------------------------------------------
template <int EPI, bool DUAL>
__global__ __launch_bounds__(256) void gemm_k(
    const float* __restrict__ A, const float* __restrict__ Bm,
    const float* __restrict__ A2, const float* __restrict__ B2,
    float* __restrict__ Cm,
    int M, int K,
    long aStride, long bStride, long cStride,
    const float* __restrict__ dinv)
{
    __shared__ float As[16][68];
    __shared__ float Bs[16][64];
    __shared__ float As2[16][68];
    __shared__ float Bs2[16][64];

    const int tid = threadIdx.x;
    const int b  = blockIdx.z;
    const int m0 = blockIdx.y * 64;
    const int n0 = blockIdx.x * 64;

    const float* Ab  = A  + (size_t)b * aStride;
    const float* Bb  = Bm + (size_t)b * bStride;
    const float* A2b = DUAL ? (A2 + (size_t)b * aStride) : nullptr;
    const float* B2b = DUAL ? (B2 + (size_t)b * bStride) : nullptr;
    float* Cb = Cm + (size_t)b * cStride;

    const int tm = tid >> 4;   // 0..15
    const int tn = tid & 15;   // 0..15

    float acc[4][4] = {};

    for (int k0 = 0; k0 < K; k0 += 16) {
#pragma unroll
        for (int j = 0; j < 4; ++j) {
            int idx = tid + j * 256;
            int ik = idx & 15, im = idx >> 4;
            As[ik][im] = Ab[(size_t)(m0 + im) * K + k0 + ik];
            if (DUAL) As2[ik][im] = A2b[(size_t)(m0 + im) * K + k0 + ik];
        }
#pragma unroll
        for (int j = 0; j < 4; ++j) {
            int idx = tid + j * 256;
            int in = idx & 63, ik = idx >> 6;
            Bs[ik][in] = Bb[(size_t)(k0 + ik) * Nc + n0 + in];
            if (DUAL) Bs2[ik][in] = B2b[(size_t)(k0 + ik) * Nc + n0 + in];
        }
        __syncthreads();
#pragma unroll
        for (int k = 0; k < 16; ++k) {
            float a[4], bb[4];
#pragma unroll
            for (int r = 0; r < 4; ++r) a[r] = As[k][tm * 4 + r];
#pragma unroll
            for (int c2 = 0; c2 < 4; ++c2) bb[c2] = Bs[k][tn * 4 + c2];
#pragma unroll
            for (int r = 0; r < 4; ++r)
#pragma unroll
                for (int c2 = 0; c2 < 4; ++c2)
                    acc[r][c2] = fmaf(a[r], bb[c2], acc[r][c2]);
            if (DUAL) {
#pragma unroll
                for (int r = 0; r < 4; ++r) a[r] = As2[k][tm * 4 + r];
#pragma unroll
                for (int c2 = 0; c2 < 4; ++c2) bb[c2] = Bs2[k][tn * 4 + c2];
#pragma unroll
                for (int r = 0; r < 4; ++r)
#pragma unroll
                    for (int c2 = 0; c2 < 4; ++c2)
                        acc[r][c2] = fmaf(a[r], bb[c2], acc[r][c2]);
            }
        }
        __syncthreads();
    }

    float dv[4];
    if (EPI == 2) {
        const float* dd = dinv + (size_t)b * Nc;
#pragma unroll
        for (int c2 = 0; c2 < 4; ++c2) dv[c2] = 0.5f * dd[n0 + tn * 4 + c2];
    }

#pragma unroll
    for (int r = 0; r < 4; ++r) {
        float4 v;
        float t0 = acc[r][0], t1 = acc[r][1], t2 = acc[r][2], t3 = acc[r][3];
        if (EPI == 1) { t0 = fmaxf(t0, 0.f); t1 = fmaxf(t1, 0.f); t2 = fmaxf(t2, 0.f); t3 = fmaxf(t3, 0.f); }
        if (EPI == 2) { t0 *= dv[0]; t1 *= dv[1]; t2 *= dv[2]; t3 *= dv[3]; }
        v.x = t0; v.y = t1; v.z = t2; v.w = t3;
        *reinterpret_cast<float4*>(&Cb[(size_t)(m0 + tm * 4 + r) * Nc + n0 + tn * 4]) = v;
    }
}

// ---------------------------------------------------------------------------
// ABT GEMM (split-K): Cpart[ks][b][m][n] = sum_{i in chunk ks}
//      G[b][m][i] * dinv[b][i] * U[b][n^128][i],  m:128, n:256, i:3136
// ---------------------------------------------------------------------------
__global__ __launch_bounds__(256) void abt_k(
    const float* __restrict__ G,    // [B][128][N]
    const float* __restrict__ U,    // [B][256][N]
    const float* __restrict__ dinv, // [B][N]
    float* __restrict__ Cpart,      // [KS][B][128][256]
    int kchunk)
{
    __shared__ float As[16][68];
    __shared__ float Bs[16][68];

    const int tid = threadIdx.x;
    const int b  = blockIdx.z;
    const int ks = blockIdx.y;
    const int m0 = (blockIdx.x >> 2) * 64;  // 0 or 64
    const int n0 = (blockIdx.x & 3) * 64;   // 0..192

    const float* Ab = G + (size_t)b * Pc * Nc;
    const float* Ub = U + (size_t)b * 2 * Pc * Nc;
    const float* dd = dinv + (size_t)b * Nc;

    const int tm = tid >> 4;
    const int tn = tid & 15;

    float acc[4][4] = {};

    const int kend = (ks + 1) * kchunk;
    for (int k0 = ks * kchunk; k0 < kend; k0 += 16) {
#pragma unroll
        for (int j = 0; j < 4; ++j) {
            int idx = tid + j * 256;
            int ik = idx & 15, im = idx >> 4;
            As[ik][im] = Ab[(size_t)(m0 + im) * Nc + k0 + ik];
            Bs[ik][im] = Ub[(size_t)((n0 + im) ^ 128) * Nc + k0 + ik] * dd[k0 + ik];
        }
        __syncthreads();
#pragma unroll
        for (int k = 0; k < 16; ++k) {
            float a[4], bb[4];
#pragma unroll
            for (int r = 0; r < 4; ++r) a[r] = As[k][tm * 4 + r];
#pragma unroll
            for (int c2 = 0; c2 < 4; ++c2) bb[c2] = Bs[k][tn * 4 + c2];
#pragma unroll
            for (int r = 0; r < 4; ++r)
#pragma unroll
                for (int c2 = 0; c2 < 4; ++c2)
                    acc[r][c2] = fmaf(a[r], bb[c2], acc[r][c2]);
        }
        __syncthreads();
    }

    float* Cb = Cpart + (size_t)(ks * Bc + b) * Pc * 2 * Pc;
#pragma unroll
    for (int r = 0; r < 4; ++r) {
        float4 v;
        v.x = acc[r][0]; v.y = acc[r][1]; v.z = acc[r][2]; v.w = acc[r][3];
        *reinterpret_cast<float4*>(&Cb[(size_t)(m0 + tm * 4 + r) * (2 * Pc) + n0 + tn * 4]) = v;
    }
}

// Reduce split-K partials: MstT[b][m][n] = sum_ks Cpart[ks][b][m][n]
__global__ __launch_bounds__(256) void reduce_mst(
    const float* __restrict__ Cpart, float* __restrict__ MstT)
{
    const size_t nf4 = (size_t)Bc * Pc * 2 * Pc / 4;  // 32768
    size_t i4 = (size_t)blockIdx.x * 256 + threadIdx.x;
    if (i4 >= nf4) return;
    const float4* src = reinterpret_cast<const float4*>(Cpart);
    float4 s = src[i4];
#pragma unroll
    for (int ks = 1; ks < KS; ++ks) {
        float4 v = src[i4 + (size_t)ks * nf4];
        s.x += v.x; s.y += v.y; s.z += v.z; s.w += v.w;
    }
    reinterpret_cast<float4*>(MstT)[i4] = s;
}

// Row sums of U: rs[b*256+q] = sum_i U[b][q][i]
__global__ __launch_bounds__(256) void rowsum_k(
    const float* __restrict__ U, float* __restrict__ rs)
{
    const int row = blockIdx.x;  // 0..B*256-1
    const float* src = U + (size_t)row * Nc;
    float s = 0.f;
    for (int i = threadIdx.x; i < Nc; i += 256) s += src[i];
    __shared__ float red[256];
    red[threadIdx.x] = s;
    __syncthreads();
    for (int st = 128; st > 0; st >>= 1) {
        if (threadIdx.x < st) red[threadIdx.x] += red[threadIdx.x + st];
        __syncthreads();
    }
    if (threadIdx.x == 0) rs[row] = red[0];
}

// dinv[b][i] = d!=0 ? rsqrt(d) : 0,  d = 0.5 * sum_q U[b][q][i] * rs[b][q^128]
__global__ __launch_bounds__(256) void dinv_k(
    const float* __restrict__ U, const float* __restrict__ rs,
    float* __restrict__ dinv)
{
    const int b = blockIdx.y;
    const int i = blockIdx.x * 256 + threadIdx.x;
    __shared__ float r[256];
    r[threadIdx.x] = rs[b * 256 + (threadIdx.x ^ 128)];
    __syncthreads();
    if (i < Nc) {
        const float* Ub = U + (size_t)b * 2 * Pc * Nc;
        float acc = 0.f;
#pragma unroll 4
        for (int q = 0; q < 256; ++q)
            acc = fmaf(Ub[(size_t)q * Nc + i], r[q], acc);
        float d = 0.5f * acc;
        dinv[(size_t)b * Nc + i] = (d != 0.0f) ? rsqrtf(d) : 0.0f;
    }
}

// Per-channel BN stats over (b, n): scale[c] = gamma/std, shift[c] = beta - mean*scale
__global__ __launch_bounds__(256) void bnstats_k(
    const float* __restrict__ o, const float* __restrict__ gamma,
    const float* __restrict__ beta, float* __restrict__ scale,
    float* __restrict__ shift)
{
    const int c = blockIdx.x;
    float s = 0.f, s2 = 0.f;
    for (int b = 0; b < Bc; ++b) {
        const float* src = o + ((size_t)b * Cc + c) * Nc;
        for (int i = threadIdx.x; i < Nc; i += 256) {
            float v = src[i];
            s += v;
            s2 = fmaf(v, v, s2);
        }
    }
    __shared__ float r1[256], r2[256];
    r1[threadIdx.x] = s; r2[threadIdx.x] = s2;
    __syncthreads();
    for (int st = 128; st > 0; st >>= 1) {
        if (threadIdx.x < st) {
            r1[threadIdx.x] += r1[threadIdx.x + st];
            r2[threadIdx.x] += r2[threadIdx.x + st];
        }
        __syncthreads();
    }
    if (threadIdx.x == 0) {
        const float inv = 1.0f / (float)(Bc * Nc);
        float mean = r1[0] * inv;
        float var = r2[0] * inv - mean * mean;
        float rstd = rsqrtf(var + EPSc);
        float sc = gamma[c] * rstd;
        scale[c] = sc;
        shift[c] = beta[c] - mean * sc;
    }
}

// out[b][c][i] += o[b][c][i]*scale[c] + shift[c]
__global__ __launch_bounds__(256) void bnapply_k(
    const float* __restrict__ o, const float* __restrict__ scale,
    const float* __restrict__ shift, float* __restrict__ out)
{
    size_t i4 = (size_t)blockIdx.x * 256 + threadIdx.x;  // float4 index
    int c = (int)((i4 * 4) / Nc) % Cc;
    float sc = scale[c], sh = shift[c];
    float4 ov = reinterpret_cast<const float4*>(o)[i4];
    float4 uv = reinterpret_cast<float4*>(out)[i4];
    uv.x += fmaf(ov.x, sc, sh);
    uv.y += fmaf(ov.y, sc, sh);
    uv.z += fmaf(ov.z, sc, sh);
    uv.w += fmaf(ov.w, sc, sh);
    reinterpret_cast<float4*>(out)[i4] = uv;
}

}  // namespace

extern "C" void kernel_launch(void* const* d_in, const int* in_sizes, int n_in,
                              void* d_out, int out_size, void* d_ws, size_t ws_size,
                              hipStream_t stream) {
    const float* x     = (const float*)d_in[0];
    const float* Wt    = (const float*)d_in[1];
    const float* Wp    = (const float*)d_in[2];
    const float* Wg    = (const float*)d_in[3];
    const float* W1    = (const float*)d_in[4];
    const float* W2    = (const float*)d_in[5];
    const float* gamma = (const float*)d_in[6];
    const float* beta  = (const float*)d_in[7];
    float* out = (float*)d_out;

    float* ws = (float*)d_ws;
    float* U     = ws;                                     // B*2P*N
    float* g     = U + (size_t)Bc * 2 * Pc * Nc;           // B*P*N
    float* ag    = g + (size_t)Bc * Pc * Nc;               // B*P*N
    float* o     = ag + (size_t)Bc * Pc * Nc;              // B*C*N
    float* dinv  = o + (size_t)Bc * Cc * Nc;               // B*N
    float* rs    = dinv + (size_t)Bc * Nc;                 // B*2P
    float* MstT  = rs + (size_t)Bc * 2 * Pc;               // B*P*2P
    float* Cpart = MstT + (size_t)Bc * Pc * 2 * Pc;        // KS*B*P*2P
    float* scale = Cpart + (size_t)KS * Bc * Pc * 2 * Pc;  // C
    float* shift = scale + Cc;                             // C

    dim3 blk(256);

    // out = xf
    hipMemcpyAsync(out, x, sizeof(float) * (size_t)Bc * Cc * Nc,
                   hipMemcpyDeviceToDevice, stream);

    // t = relu(Wt @ x), p = relu(Wp @ x)  -> U rows [0,128) and [128,256)
    gemm_k<1, false><<<dim3(49, Pc / 64, Bc), blk, 0, stream>>>(
        Wt, x, nullptr, nullptr, U, Pc, Cc,
        0L, (long)Cc * Nc, (long)2 * Pc * Nc, nullptr);
    gemm_k<1, false><<<dim3(49, Pc / 64, Bc), blk, 0, stream>>>(
        Wp, x, nullptr, nullptr, U + (size_t)Pc * Nc, Pc, Cc,
        0L, (long)Cc * Nc, (long)2 * Pc * Nc, nullptr);

    // degree -> dinv
    rowsum_k<<<dim3(Bc * 2 * Pc), blk, 0, stream>>>(U, rs);
    dinv_k<<<dim3((Nc + 255) / 256, Bc), blk, 0, stream>>>(U, rs, dinv);

    for (int s = 0; s < Sc; ++s) {
        // g = Wg[s] @ out
        gemm_k<0, false><<<dim3(49, Pc / 64, Bc), blk, 0, stream>>>(
            Wg + (size_t)s * Pc * Cc, out, nullptr, nullptr, g, Pc, Cc,
            0L, (long)Cc * Nc, (long)Pc * Nc, nullptr);
        // MstT[p',q'] = sum_i g[p',i]*dinv[i]*U[q'^128,i]  (split-K + reduce)
        abt_k<<<dim3(8, KS, Bc), blk, 0, stream>>>(g, U, dinv, Cpart, Nc / KS);
        reduce_mst<<<dim3(128), blk, 0, stream>>>(Cpart, MstT);
        // ag = 0.5*dinv ⊙ (MstT @ U)
        gemm_k<2, false><<<dim3(49, Pc / 64, Bc), blk, 0, stream>>>(
            MstT, U, nullptr, nullptr, ag, Pc, 2 * Pc,
            (long)Pc * 2 * Pc, (long)2 * Pc * Nc, (long)Pc * Nc, dinv);
        // o = W1[s] @ ag + W2[s] @ g
        gemm_k<0, true><<<dim3(49, Cc / 64, Bc), blk, 0, stream>>>(
            W1 + (size_t)s * Cc * Pc, ag, W2 + (size_t)s * Cc * Pc, g, o, Cc, Pc,
            0L, (long)Pc * Nc, (long)Cc * Nc, nullptr);
        // BN stats + apply (out += BN(o))
        bnstats_k<<<dim3(Cc), blk, 0, stream>>>(o, gamma + s * Cc, beta + s * Cc,
                                                scale, shift);
        bnapply_k<<<dim3((Bc * Cc * Nc / 4) / 256), blk, 0, stream>>>(
            o, scale, shift, out);
    }
}

// Round 2
// 315.608 us; speedup vs baseline: 2.2704x; 2.2704x over previous
//
#include <hip/hip_runtime.h>

namespace {

constexpr int Bc = 4;
constexpr int Cc = 256;
constexpr int Pc = 128;
constexpr int Nc = 3136;   // 56*56 = 49*64
constexpr int Sc = 5;
constexpr int KSn = 7;     // split-K chunks for abt (3136 = 7*448)
constexpr int KCH = 448;
constexpr float EPSc = 1e-5f;

typedef __attribute__((ext_vector_type(8))) short bf16x8;
typedef __attribute__((ext_vector_type(4))) float f32x4;
typedef __attribute__((ext_vector_type(8))) unsigned short u16x8;
typedef __attribute__((ext_vector_type(4))) unsigned short u16x4;

__device__ inline float bf2f(unsigned short u) {
    return __uint_as_float(((unsigned)u) << 16);
}
__device__ inline unsigned short f2bf(float f) {
    unsigned u = __float_as_uint(f);
    return (unsigned short)((u + 0x7FFFu + ((u >> 16) & 1u)) >> 16);
}

// ---------------------------------------------------------------------------
// MFMA GEMM: D[m][n] = sum_k A[m][k] * B[n][k]   (both operands K-contiguous)
//   tile 64(m) x 64(n), 4 waves, K-step 32, double-buffered LDS via
//   global_load_lds(16B) with granule swizzle kg ^= (row>>1)&3.
// EPI: 0 none, 1 relu, 2 scale rows by 0.5*dinv[b][m0+row]
// CMOUT: also write column-major output scaled by dinv[b][m] (ld = Nc)
// SPLITK: z = ks*Bc+b, k range [ks*kchunk, +kchunk), out offset ks*smSlice
// TRANSB: B operand is spatial-major U_sm[i][q] (ldb=row stride); staged with
//         an in-LDS transpose so logical B[q][i] is K(i)-contiguous.
// ---------------------------------------------------------------------------
template <int EPI, bool DUAL, bool CMOUT, bool SPLITK, bool TRANSB>
__global__ __launch_bounds__(256) void mgemm(
    const unsigned short* __restrict__ A, int lda, long aB,
    const unsigned short* __restrict__ Bw, int ldb, long bB,
    const unsigned short* __restrict__ A2, const unsigned short* __restrict__ B2,
    unsigned short* __restrict__ outSM, int ldsm, long smB, long smSlice,
    unsigned short* __restrict__ outCM, long cmB,
    int K, int kchunk, const float* __restrict__ dinv)
{
    constexpr int NT = DUAL ? 4 : 2;          // tiles per buffer
    constexpr int STB = 2 * NT * 4096;        // staging bytes
    constexpr int LDSZ = STB > 16640 ? STB : 16640;
    __shared__ __align__(16) char lds[LDSZ];

    int b, kstart, kend;
    long smOff;
    if (SPLITK) {
        b = blockIdx.z & 3;
        int ks = blockIdx.z >> 2;
        kstart = ks * kchunk;
        kend = kstart + kchunk;
        smOff = (long)ks * smSlice;
    } else {
        b = blockIdx.z; kstart = 0; kend = K; smOff = 0;
    }
    const int n0 = blockIdx.x * 64;
    const int m0 = blockIdx.y * 64;
    const int tid = threadIdx.x;
    const int w = tid >> 6, l = tid & 63;

    const unsigned short* Ab  = A + (size_t)b * aB + (size_t)m0 * lda;
    const unsigned short* A2b = DUAL ? (A2 + (size_t)b * aB + (size_t)m0 * lda) : nullptr;
    const unsigned short* Bb  = TRANSB ? (Bw + (size_t)b * bB + n0)
                                       : (Bw + (size_t)b * bB + (size_t)n0 * ldb);
    const unsigned short* B2b = DUAL ? (B2 + (size_t)b * bB + (size_t)n0 * ldb) : nullptr;

    const int srow = tid >> 2;                       // staged tile row 0..63
    const int skg  = (tid & 3) ^ ((srow >> 1) & 3);  // swizzled k-granule
    const size_t aGo = (size_t)srow * lda + skg * 8;
    const size_t bGo = (size_t)srow * ldb + skg * 8;

    f32x4 acc[4] = {};

    auto stage = [&](int buf, int k0) {
        char* base = lds + buf * (NT * 4096);
        __builtin_amdgcn_global_load_lds(
            (const __attribute__((address_space(1))) void*)(Ab + aGo + k0),
            (__attribute__((address_space(3))) void*)(base + w * 1024), 16, 0, 0);
        if (DUAL) {
            __builtin_amdgcn_global_load_lds(
                (const __attribute__((address_space(1))) void*)(A2b + aGo + k0),
                (__attribute__((address_space(3))) void*)(base + 2 * 4096 + w * 1024), 16, 0, 0);
        }
        if (!TRANSB) {
            __builtin_amdgcn_global_load_lds(
                (const __attribute__((address_space(1))) void*)(Bb + bGo + k0),
                (__attribute__((address_space(3))) void*)(base + 4096 + w * 1024), 16, 0, 0);
            if (DUAL) {
                __builtin_amdgcn_global_load_lds(
                    (const __attribute__((address_space(1))) void*)(B2b + bGo + k0),
                    (__attribute__((address_space(3))) void*)(base + 3 * 4096 + w * 1024), 16, 0, 0);
            }
        } else {
            const int ii = tid >> 3, q8 = (tid & 7) * 8;
            u16x8 v = *(const u16x8*)(Bb + (size_t)(k0 + ii) * ldb + q8);
            unsigned short* bt = (unsigned short*)(lds + buf * (NT * 4096) + 4096);
            const int kg = ii >> 3;
#pragma unroll
            for (int j = 0; j < 8; ++j) {
                int q = q8 + j;
                int kgp = kg ^ ((q >> 1) & 3);
                bt[(q * 4 + kgp) * 8 + (ii & 7)] = v[j];
            }
        }
    };

    auto compute = [&](int buf) {
        const char* base = lds + buf * (NT * 4096);
        const int kg = l >> 4;
        const int lo = l & 15;
        const int bcol = w * 16 + lo;
        bf16x8 bf = *(const bf16x8*)(base + 4096 +
            (((size_t)bcol * 4 + (kg ^ ((bcol >> 1) & 3))) << 4));
        bf16x8 af[4];
#pragma unroll
        for (int r = 0; r < 4; ++r) {
            int row = r * 16 + lo;
            af[r] = *(const bf16x8*)(base +
                (((size_t)row * 4 + (kg ^ ((row >> 1) & 3))) << 4));
        }
#pragma unroll
        for (int r = 0; r < 4; ++r)
            acc[r] = __builtin_amdgcn_mfma_f32_16x16x32_bf16(af[r], bf, acc[r], 0, 0, 0);
        if (DUAL) {
            bf16x8 bf2 = *(const bf16x8*)(base + 3 * 4096 +
                (((size_t)bcol * 4 + (kg ^ ((bcol >> 1) & 3))) << 4));
#pragma unroll
            for (int r = 0; r < 4; ++r) {
                int row = r * 16 + lo;
                bf16x8 a2 = *(const bf16x8*)(base + 2 * 4096 +
                    (((size_t)row * 4 + (kg ^ ((row >> 1) & 3))) << 4));
                acc[r] = __builtin_amdgcn_mfma_f32_16x16x32_bf16(a2, bf2, acc[r], 0, 0, 0);
            }
        }
    };

    stage(0, kstart);
    __syncthreads();
    const int nst = (kend - kstart) >> 5;
    for (int s = 0; s < nst; ++s) {
        if (s + 1 < nst) stage((s + 1) & 1, kstart + ((s + 1) << 5));
        compute(s & 1);
        __syncthreads();
    }

    // stage accumulators to LDS f32 [64][65] and write coalesced
    float* ot = (float*)lds;
#pragma unroll
    for (int r = 0; r < 4; ++r) {
#pragma unroll
        for (int j = 0; j < 4; ++j) {
            float v = acc[r][j];
            if (EPI == 1) v = fmaxf(v, 0.f);
            ot[(r * 16 + (l >> 4) * 4 + j) * 65 + (w * 16 + (l & 15))] = v;
        }
    }
    __syncthreads();

    {
        const int r = tid >> 2, c0 = (tid & 3) * 16;
        float sc = 1.f;
        if (EPI == 2) sc = 0.5f * dinv[(size_t)b * Nc + m0 + r];
        u16x8 o1, o2;
#pragma unroll
        for (int j = 0; j < 8; ++j) {
            float v = ot[r * 65 + c0 + j];
            if (EPI == 2) v *= sc;
            o1[j] = f2bf(v);
        }
#pragma unroll
        for (int j = 0; j < 8; ++j) {
            float v = ot[r * 65 + c0 + 8 + j];
            if (EPI == 2) v *= sc;
            o2[j] = f2bf(v);
        }
        unsigned short* dst = outSM + (size_t)b * smB + smOff +
                              (size_t)(m0 + r) * ldsm + n0 + c0;
        *(u16x8*)dst = o1;
        *(u16x8*)(dst + 8) = o2;
    }
    if (CMOUT) {
        const int c = tid >> 2, r0 = (tid & 3) * 16;
        const float* dv = dinv + (size_t)b * Nc + m0 + r0;
        u16x8 o1, o2;
#pragma unroll
        for (int j = 0; j < 8; ++j) o1[j] = f2bf(ot[(r0 + j) * 65 + c] * dv[j]);
#pragma unroll
        for (int j = 0; j < 8; ++j) o2[j] = f2bf(ot[(r0 + 8 + j) * 65 + c] * dv[8 + j]);
        unsigned short* dst = outCM + (size_t)b * cmB + (size_t)(n0 + c) * Nc + m0 + r0;
        *(u16x8*)dst = o1;
        *(u16x8*)(dst + 8) = o2;
    }
}

// ---------------------------------------------------------------------------
// weights f32 -> bf16 (Wt+Wp concatenated into Wcomb[256][256])
// ---------------------------------------------------------------------------
__global__ __launch_bounds__(256) void cvtw_k(
    const float* __restrict__ Wt, const float* __restrict__ Wp,
    const float* __restrict__ Wg, const float* __restrict__ W1,
    const float* __restrict__ W2,
    unsigned short* __restrict__ Wcomb, unsigned short* __restrict__ Wgh,
    unsigned short* __restrict__ W1h, unsigned short* __restrict__ W2h)
{
    size_t e = ((size_t)blockIdx.x * 256 + threadIdx.x) * 4;
    const float* src; unsigned short* dst;
    if (e < 32768)            { src = Wt + e;                    dst = Wcomb + e; }
    else if (e < 65536)       { src = Wp + (e - 32768);          dst = Wcomb + e; }
    else if (e < 65536 + 163840)     { size_t o = e - 65536;          src = Wg + o; dst = Wgh + o; }
    else if (e < 65536 + 2 * 163840) { size_t o = e - 65536 - 163840; src = W1 + o; dst = W1h + o; }
    else                             { size_t o = e - 65536 - 327680; src = W2 + o; dst = W2h + o; }
    float4 v = *(const float4*)src;
    u16x4 t;
    t[0] = f2bf(v.x); t[1] = f2bf(v.y); t[2] = f2bf(v.z); t[3] = f2bf(v.w);
    *(u16x4*)dst = t;
}

// x[b][c][n] f32 -> out_sm[b][n][c] f32 + outh bf16
__global__ __launch_bounds__(256) void xpin_k(
    const float* __restrict__ x, float* __restrict__ out_sm,
    unsigned short* __restrict__ outh)
{
    __shared__ float tb[64][65];
    int b = blockIdx.z, c0 = blockIdx.y * 64, n0 = blockIdx.x * 64;
    int t = threadIdx.x;
    {
        int ci = t >> 2, nb = (t & 3) * 16;
        const float* src = x + ((size_t)b * Cc + c0 + ci) * Nc + n0 + nb;
#pragma unroll
        for (int k = 0; k < 4; ++k) {
            float4 v = *(const float4*)(src + 4 * k);
            tb[ci][nb + 4 * k + 0] = v.x; tb[ci][nb + 4 * k + 1] = v.y;
            tb[ci][nb + 4 * k + 2] = v.z; tb[ci][nb + 4 * k + 3] = v.w;
        }
    }
    __syncthreads();
    {
        int r = t >> 2, cb = (t & 3) * 16;
        size_t off = ((size_t)b * Nc + n0 + r) * Cc + c0 + cb;
        float vv[16];
#pragma unroll
        for (int j = 0; j < 16; ++j) vv[j] = tb[cb + j][r];
        float* dst = out_sm + off;
#pragma unroll
        for (int k = 0; k < 4; ++k) {
            float4 v; v.x = vv[4*k]; v.y = vv[4*k+1]; v.z = vv[4*k+2]; v.w = vv[4*k+3];
            *(float4*)(dst + 4 * k) = v;
        }
        u16x8 h1, h2;
#pragma unroll
        for (int j = 0; j < 8; ++j) { h1[j] = f2bf(vv[j]); h2[j] = f2bf(vv[8 + j]); }
        unsigned short* dh = outh + off;
        *(u16x8*)dh = h1;
        *(u16x8*)(dh + 8) = h2;
    }
}

// out_sm[b][n][c] f32 -> d_out[b][c][n] f32
__global__ __launch_bounds__(256) void xpout_k(
    const float* __restrict__ out_sm, float* __restrict__ outp)
{
    __shared__ float tb[64][65];
    int b = blockIdx.z, c0 = blockIdx.y * 64, n0 = blockIdx.x * 64;
    int t = threadIdx.x;
    {
        int r = t >> 2, cb = (t & 3) * 16;
        const float* src = out_sm + ((size_t)b * Nc + n0 + r) * Cc + c0 + cb;
#pragma unroll
        for (int k = 0; k < 4; ++k) {
            float4 v = *(const float4*)(src + 4 * k);
            tb[r][cb + 4 * k + 0] = v.x; tb[r][cb + 4 * k + 1] = v.y;
            tb[r][cb + 4 * k + 2] = v.z; tb[r][cb + 4 * k + 3] = v.w;
        }
    }
    __syncthreads();
    {
        int c = t >> 2, rb = (t & 3) * 16;
        float vv[16];
#pragma unroll
        for (int j = 0; j < 16; ++j) vv[j] = tb[rb + j][c];
        float* dst = outp + ((size_t)b * Cc + c0 + c) * Nc + n0 + rb;
#pragma unroll
        for (int k = 0; k < 4; ++k) {
            float4 v; v.x = vv[4*k]; v.y = vv[4*k+1]; v.z = vv[4*k+2]; v.w = vv[4*k+3];
            *(float4*)(dst + 4 * k) = v;
        }
    }
}

// partial column sums of U_sm: rp[b][bx][q] = sum_{i in 64-chunk} U_sm[b][i][q]
__global__ __launch_bounds__(256) void rowsum_part_k(
    const unsigned short* __restrict__ U, float* __restrict__ rp)
{
    int b = blockIdx.y, q = threadIdx.x;
    size_t i0 = blockIdx.x * 64;
    const unsigned short* base = U + ((size_t)b * Nc + i0) * 256 + q;
    float s = 0.f;
#pragma unroll
    for (int i = 0; i < 64; ++i) s += bf2f(base[(size_t)i * 256]);
    rp[((size_t)b * 49 + blockIdx.x) * 256 + q] = s;
}

// dinv[b][i] = d>0 ? rsqrt(d) : 0, d = 0.5 * sum_q U_sm[b][i][q] * rs[b][q^128]
__global__ __launch_bounds__(256) void dinv_k(
    const unsigned short* __restrict__ U, const float* __restrict__ rp,
    float* __restrict__ dinv)
{
    __shared__ float rsl[256];
    int b = blockIdx.y, tid = threadIdx.x;
    float s = 0.f;
    for (int j = 0; j < 49; ++j) s += rp[((size_t)b * 49 + j) * 256 + tid];
    rsl[tid ^ 128] = s;
    __syncthreads();
    int i = blockIdx.x * 256 + tid;
    if (i < Nc) {
        const unsigned short* row = U + ((size_t)b * Nc + i) * 256;
        float acc = 0.f;
        for (int q0 = 0; q0 < 256; q0 += 8) {
            u16x8 v = *(const u16x8*)(row + q0);
#pragma unroll
            for (int j = 0; j < 8; ++j) acc = fmaf(bf2f(v[j]), rsl[q0 + j], acc);
        }
        float d = 0.5f * acc;
        dinv[(size_t)b * Nc + i] = d > 0.f ? rsqrtf(d) : 0.f;
    }
}

// MstT[b][p][q] = sum_ks Cpart[ks][b][p][q^128]   (bf16 in/out, f32 sum)
__global__ __launch_bounds__(256) void redmst_k(
    const unsigned short* __restrict__ Cpart, unsigned short* __restrict__ MstT)
{
    int e8 = blockIdx.x * 256 + threadIdx.x;    // 16384 total
    int bp = e8 >> 5, qc = e8 & 31;
    size_t dstOff = ((size_t)bp * 32 + qc) * 8;
    size_t srcOff = ((size_t)bp * 32 + (qc ^ 16)) * 8;
    float s[8] = {};
    for (int ks = 0; ks < KSn; ++ks) {
        u16x8 v = *(const u16x8*)(Cpart + (size_t)ks * (Bc * Pc * Cc) + srcOff);
#pragma unroll
        for (int j = 0; j < 8; ++j) s[j] += bf2f(v[j]);
    }
    u16x8 o;
#pragma unroll
    for (int j = 0; j < 8; ++j) o[j] = f2bf(s[j]);
    *(u16x8*)(MstT + dstOff) = o;
}

// BN partial stats over 128-row chunks of o[b*n][256]
__global__ __launch_bounds__(256) void bnsp_k(
    const unsigned short* __restrict__ o, float* __restrict__ ps,
    float* __restrict__ ps2)
{
    __shared__ float l1[8][256], l2[8][256];
    int g = blockIdx.x, t = threadIdx.x;
    int c8 = (t & 31) * 8, rsu = t >> 5;
    float s[8] = {}, s2[8] = {};
    for (int j = 0; j < 16; ++j) {
        size_t row = (size_t)g * 128 + rsu + 8 * j;
        u16x8 v = *(const u16x8*)(o + row * 256 + c8);
#pragma unroll
        for (int u = 0; u < 8; ++u) {
            float f = bf2f(v[u]);
            s[u] += f;
            s2[u] = fmaf(f, f, s2[u]);
        }
    }
#pragma unroll
    for (int u = 0; u < 8; ++u) { l1[rsu][c8 + u] = s[u]; l2[rsu][c8 + u] = s2[u]; }
    __syncthreads();
    float a = 0.f, a2 = 0.f;
#pragma unroll
    for (int r = 0; r < 8; ++r) { a += l1[r][t]; a2 += l2[r][t]; }
    ps[(size_t)g * 256 + t] = a;
    ps2[(size_t)g * 256 + t] = a2;
}

__global__ __launch_bounds__(256) void bnfin_k(
    const float* __restrict__ ps, const float* __restrict__ ps2,
    const float* __restrict__ gamma, const float* __restrict__ beta,
    float* __restrict__ scale, float* __restrict__ shift)
{
    int c = threadIdx.x;
    float a = 0.f, a2 = 0.f;
    for (int g = 0; g < 98; ++g) {
        a += ps[(size_t)g * 256 + c];
        a2 += ps2[(size_t)g * 256 + c];
    }
    const float inv = 1.f / (float)(Bc * Nc);
    float mean = a * inv;
    float var = a2 * inv - mean * mean;
    float sc = gamma[c] * rsqrtf(var + EPSc);
    scale[c] = sc;
    shift[c] = beta[c] - mean * sc;
}

// out_sm += BN(o); outh = bf16(out_sm)
__global__ __launch_bounds__(256) void bnapp_k(
    const unsigned short* __restrict__ o, const float* __restrict__ scale,
    const float* __restrict__ shift, float* __restrict__ out_sm,
    unsigned short* __restrict__ outh)
{
    __shared__ float lsc[256], lsh[256];
    int t = threadIdx.x;
    lsc[t] = scale[t];
    lsh[t] = shift[t];
    __syncthreads();
    size_t e = ((size_t)blockIdx.x * 256 + t) * 8;
    int c8 = (int)(e & 255);
    u16x8 ov = *(const u16x8*)(o + e);
    float* op = out_sm + e;
    float4 o1 = *(float4*)op, o2 = *(float4*)(op + 4);
    float r[8];
#pragma unroll
    for (int j = 0; j < 8; ++j) r[j] = fmaf(bf2f(ov[j]), lsc[c8 + j], lsh[c8 + j]);
    o1.x += r[0]; o1.y += r[1]; o1.z += r[2]; o1.w += r[3];
    o2.x += r[4]; o2.y += r[5]; o2.z += r[6]; o2.w += r[7];
    *(float4*)op = o1;
    *(float4*)(op + 4) = o2;
    u16x8 hv;
    hv[0] = f2bf(o1.x); hv[1] = f2bf(o1.y); hv[2] = f2bf(o1.z); hv[3] = f2bf(o1.w);
    hv[4] = f2bf(o2.x); hv[5] = f2bf(o2.y); hv[6] = f2bf(o2.z); hv[7] = f2bf(o2.w);
    *(u16x8*)(outh + e) = hv;
}

}  // namespace

extern "C" void kernel_launch(void* const* d_in, const int* in_sizes, int n_in,
                              void* d_out, int out_size, void* d_ws, size_t ws_size,
                              hipStream_t stream) {
    const float* x     = (const float*)d_in[0];
    const float* Wt    = (const float*)d_in[1];
    const float* Wp    = (const float*)d_in[2];
    const float* Wg    = (const float*)d_in[3];
    const float* W1    = (const float*)d_in[4];
    const float* W2    = (const float*)d_in[5];
    const float* gamma = (const float*)d_in[6];
    const float* beta  = (const float*)d_in[7];

    char* p = (char*)d_ws;
    auto alloc = [&](size_t bytes) { char* r = p; p += (bytes + 255) & ~(size_t)255; return r; };
    float*          out_sm = (float*)         alloc((size_t)Bc * Nc * Cc * 4);
    unsigned short* outh   = (unsigned short*)alloc((size_t)Bc * Nc * Cc * 2);
    unsigned short* U_sm   = (unsigned short*)alloc((size_t)Bc * Nc * 256 * 2);
    unsigned short* g_sm   = (unsigned short*)alloc((size_t)Bc * Nc * Pc * 2);
    unsigned short* g_cmd  = (unsigned short*)alloc((size_t)Bc * Pc * Nc * 2);
    unsigned short* ag_sm  = (unsigned short*)alloc((size_t)Bc * Nc * Pc * 2);
    unsigned short* o_sm   = (unsigned short*)alloc((size_t)Bc * Nc * Cc * 2);
    unsigned short* Cpart  = (unsigned short*)alloc((size_t)KSn * Bc * Pc * Cc * 2);
    unsigned short* MstT   = (unsigned short*)alloc((size_t)Bc * Pc * Cc * 2);
    unsigned short* Wcomb  = (unsigned short*)alloc((size_t)Cc * Cc * 2);
    unsigned short* Wgh    = (unsigned short*)alloc((size_t)Sc * Pc * Cc * 2);
    unsigned short* W1h    = (unsigned short*)alloc((size_t)Sc * Cc * Pc * 2);
    unsigned short* W2h    = (unsigned short*)alloc((size_t)Sc * Cc * Pc * 2);
    float*          rp     = (float*)         alloc((size_t)Bc * 49 * 256 * 4);
    float*          dinv   = (float*)         alloc((size_t)Bc * Nc * 4);
    float*          ps     = (float*)         alloc((size_t)98 * 256 * 4);
    float*          ps2    = (float*)         alloc((size_t)98 * 256 * 4);
    float*          scale  = (float*)         alloc(256 * 4);
    float*          shiftb = (float*)         alloc(256 * 4);

    const long NC256 = (long)Nc * 256;
    const long NC128 = (long)Nc * 128;
    dim3 blk(256);

    cvtw_k<<<544, blk, 0, stream>>>(Wt, Wp, Wg, W1, W2, Wcomb, Wgh, W1h, W2h);
    xpin_k<<<dim3(49, 4, Bc), blk, 0, stream>>>(x, out_sm, outh);

    // U = relu([Wt;Wp] @ x)  (spatial-major)
    mgemm<1, false, false, false, false><<<dim3(4, 49, Bc), blk, 0, stream>>>(
        outh, 256, NC256, Wcomb, 256, 0, nullptr, nullptr,
        U_sm, 256, NC256, 0, nullptr, 0, 256, 0, nullptr);

    rowsum_part_k<<<dim3(49, Bc), blk, 0, stream>>>(U_sm, rp);
    dinv_k<<<dim3(13, Bc), blk, 0, stream>>>(U_sm, rp, dinv);

    for (int s = 0; s < Sc; ++s) {
        // g = Wg[s] @ out; also g_cmd[p][i] = g * dinv[i] (channel-major)
        mgemm<0, false, true, false, false><<<dim3(2, 49, Bc), blk, 0, stream>>>(
            outh, 256, NC256, Wgh + (size_t)s * Pc * Cc, 256, 0, nullptr, nullptr,
            g_sm, 128, NC128, 0, g_cmd, (long)Pc * Nc, 256, 0, dinv);
        // Cpart[ks] = partial_i g_cmd[p][i] * U[q][i]  (B via LDS transpose of U_sm)
        mgemm<0, false, false, true, true><<<dim3(4, 2, KSn * Bc), blk, 0, stream>>>(
            g_cmd, Nc, (long)Pc * Nc, U_sm, 256, NC256, nullptr, nullptr,
            Cpart, 256, (long)Pc * Cc, (long)Bc * Pc * Cc, nullptr, 0,
            Nc, KCH, nullptr);
        redmst_k<<<64, blk, 0, stream>>>(Cpart, MstT);
        // ag[n][p'] = 0.5*dinv[n] * sum_q U_sm[n][q] * MstT[p'][q]
        mgemm<2, false, false, false, false><<<dim3(2, 49, Bc), blk, 0, stream>>>(
            U_sm, 256, NC256, MstT, 256, (long)Pc * Cc, nullptr, nullptr,
            ag_sm, 128, NC128, 0, nullptr, 0, 256, 0, dinv);
        // o = W1[s] @ ag + W2[s] @ g  (spatial-major bf16)
        mgemm<0, true, false, false, false><<<dim3(4, 49, Bc), blk, 0, stream>>>(
            ag_sm, 128, NC128, W1h + (size_t)s * Cc * Pc, 128, 0,
            g_sm, W2h + (size_t)s * Cc * Pc,
            o_sm, 256, NC256, 0, nullptr, 0, 128, 0, nullptr);
        bnsp_k<<<98, blk, 0, stream>>>(o_sm, ps, ps2);
        bnfin_k<<<1, blk, 0, stream>>>(ps, ps2, gamma + s * Cc, beta + s * Cc,
                                       scale, shiftb);
        bnapp_k<<<1568, blk, 0, stream>>>(o_sm, scale, shiftb, out_sm, outh);
    }

    xpout_k<<<dim3(49, 4, Bc), blk, 0, stream>>>(out_sm, (float*)d_out);
}

// Round 3
// 300.696 us; speedup vs baseline: 2.3830x; 1.0496x over previous
//
#include <hip/hip_runtime.h>

namespace {

constexpr int Bc = 4;
constexpr int Cc = 256;
constexpr int Pc = 128;
constexpr int Nc = 3136;   // 56*56 = 49*64
constexpr int Sc = 5;
constexpr int KSn = 7;     // split-K chunks for abt (3136 = 7*448)
constexpr int KCH = 448;
constexpr float EPSc = 1e-5f;

typedef __attribute__((ext_vector_type(8))) short bf16x8;
typedef __attribute__((ext_vector_type(4))) float f32x4;
typedef __attribute__((ext_vector_type(8))) unsigned short u16x8;
typedef __attribute__((ext_vector_type(4))) unsigned short u16x4;

__device__ inline float bf2f(unsigned short u) {
    return __uint_as_float(((unsigned)u) << 16);
}
__device__ inline unsigned short f2bf(float f) {
    unsigned u = __float_as_uint(f);
    return (unsigned short)((u + 0x7FFFu + ((u >> 16) & 1u)) >> 16);
}

// ---------------------------------------------------------------------------
// MFMA GEMM: D[m][n] = sum_k A[m][k] * B[n][k]   (both operands K-contiguous)
//   tile 64(m) x 64(n), 4 waves, K-step 64, double-buffered LDS via
//   global_load_lds(16B), granule swizzle phys = g ^ (row&7)  (8 granules/row).
// EPI:    0 none, 1 relu, 2 scale rows by 0.5*dinv[b][m0+row]
// CMOUT:  0 none, 1 plain column-major copy, 2 column-major scaled by dinv[m]
// SPLITK: z = ks*Bc+b, k range [ks*kchunk, +kchunk), out offset ks*smSlice
// BNSTAT: 0 none, 1 column sums -> ps, 2 column sums+sumsq -> ps,ps2
// F32OUT: write f32 output (outSM reinterpreted as float*)
// ---------------------------------------------------------------------------
template <int EPI, bool DUAL, int CMOUT, bool SPLITK, int BNSTAT, bool F32OUT>
__global__ __launch_bounds__(256) void mgemm(
    const unsigned short* __restrict__ A, int lda, long aB,
    const unsigned short* __restrict__ Bw, int ldb, long bB,
    const unsigned short* __restrict__ A2, const unsigned short* __restrict__ B2,
    unsigned short* __restrict__ outSM, int ldsm, long smB, long smSlice,
    unsigned short* __restrict__ outCM, long cmB,
    float* __restrict__ ps, float* __restrict__ ps2,
    int K, int kchunk, const float* __restrict__ dinv)
{
    constexpr int TB = 64 * 64 * 2;           // 8192 bytes per tile
    constexpr int NT = DUAL ? 4 : 2;          // tiles per buffer
    __shared__ __align__(16) char lds[2 * NT * TB];

    int b, kstart, kend;
    long smOff;
    if (SPLITK) {
        b = blockIdx.z & 3;
        int ks = blockIdx.z >> 2;
        kstart = ks * kchunk;
        kend = kstart + kchunk;
        smOff = (long)ks * smSlice;
    } else {
        b = blockIdx.z; kstart = 0; kend = K; smOff = 0;
    }
    const int n0 = blockIdx.x * 64;
    const int m0 = blockIdx.y * 64;
    const int tid = threadIdx.x;
    const int w = tid >> 6, l = tid & 63;

    const unsigned short* Ab  = A + (size_t)b * aB + (size_t)m0 * lda;
    const unsigned short* A2b = DUAL ? (A2 + (size_t)b * aB + (size_t)m0 * lda) : nullptr;
    const unsigned short* Bb  = Bw + (size_t)b * bB + (size_t)n0 * ldb;
    const unsigned short* B2b = DUAL ? (B2 + (size_t)b * bB + (size_t)n0 * ldb) : nullptr;

    // staging: wave w fills rows [w*16, w*16+16); lane l -> row +(l>>3), granule l&7
    const int srow = w * 16 + (l >> 3);
    const int gsw = ((l & 7) ^ (l >> 3)) * 8;       // swizzled source granule
    const size_t aO0 = (size_t)srow * lda + gsw;
    const size_t aO1 = aO0 + (size_t)8 * lda;
    const size_t bO0 = (size_t)srow * ldb + gsw;
    const size_t bO1 = bO0 + (size_t)8 * ldb;
    const int wch = w * 2048;

    f32x4 acc[4] = {};

    auto stage = [&](int buf, int k0) {
        char* base = lds + buf * (NT * TB);
        __builtin_amdgcn_global_load_lds(
            (const __attribute__((address_space(1))) void*)(Ab + k0 + aO0),
            (__attribute__((address_space(3))) void*)(base + wch), 16, 0, 0);
        __builtin_amdgcn_global_load_lds(
            (const __attribute__((address_space(1))) void*)(Ab + k0 + aO1),
            (__attribute__((address_space(3))) void*)(base + wch + 1024), 16, 0, 0);
        __builtin_amdgcn_global_load_lds(
            (const __attribute__((address_space(1))) void*)(Bb + k0 + bO0),
            (__attribute__((address_space(3))) void*)(base + TB + wch), 16, 0, 0);
        __builtin_amdgcn_global_load_lds(
            (const __attribute__((address_space(1))) void*)(Bb + k0 + bO1),
            (__attribute__((address_space(3))) void*)(base + TB + wch + 1024), 16, 0, 0);
        if (DUAL) {
            __builtin_amdgcn_global_load_lds(
                (const __attribute__((address_space(1))) void*)(A2b + k0 + aO0),
                (__attribute__((address_space(3))) void*)(base + 2 * TB + wch), 16, 0, 0);
            __builtin_amdgcn_global_load_lds(
                (const __attribute__((address_space(1))) void*)(A2b + k0 + aO1),
                (__attribute__((address_space(3))) void*)(base + 2 * TB + wch + 1024), 16, 0, 0);
            __builtin_amdgcn_global_load_lds(
                (const __attribute__((address_space(1))) void*)(B2b + k0 + bO0),
                (__attribute__((address_space(3))) void*)(base + 3 * TB + wch), 16, 0, 0);
            __builtin_amdgcn_global_load_lds(
                (const __attribute__((address_space(1))) void*)(B2b + k0 + bO1),
                (__attribute__((address_space(3))) void*)(base + 3 * TB + wch + 1024), 16, 0, 0);
        }
    };

    auto compute = [&](int buf) {
        const char* base = lds + buf * (NT * TB);
        const int lo = l & 15, gq = l >> 4;
        const int brow = w * 16 + lo;
#pragma unroll
        for (int kh = 0; kh < 2; ++kh) {
            const int lg = kh * 4 + gq;
            bf16x8 bf = *(const bf16x8*)(base + TB + brow * 128 + ((lg ^ (brow & 7)) << 4));
#pragma unroll
            for (int r = 0; r < 4; ++r) {
                int row = r * 16 + lo;
                bf16x8 af = *(const bf16x8*)(base + row * 128 + ((lg ^ (row & 7)) << 4));
                acc[r] = __builtin_amdgcn_mfma_f32_16x16x32_bf16(af, bf, acc[r], 0, 0, 0);
            }
            if (DUAL) {
                bf16x8 bf2 = *(const bf16x8*)(base + 3 * TB + brow * 128 + ((lg ^ (brow & 7)) << 4));
#pragma unroll
                for (int r = 0; r < 4; ++r) {
                    int row = r * 16 + lo;
                    bf16x8 a2 = *(const bf16x8*)(base + 2 * TB + row * 128 + ((lg ^ (row & 7)) << 4));
                    acc[r] = __builtin_amdgcn_mfma_f32_16x16x32_bf16(a2, bf2, acc[r], 0, 0, 0);
                }
            }
        }
    };

    stage(0, kstart);
    __syncthreads();
    const int nst = (kend - kstart) >> 6;
    for (int s = 0; s < nst; ++s) {
        if (s + 1 < nst) stage((s + 1) & 1, kstart + ((s + 1) << 6));
        compute(s & 1);
        __syncthreads();
    }

    // stage accumulators to LDS f32 [64][65]
    float* ot = (float*)lds;
#pragma unroll
    for (int r = 0; r < 4; ++r) {
#pragma unroll
        for (int j = 0; j < 4; ++j) {
            float v = acc[r][j];
            if (EPI == 1) v = fmaxf(v, 0.f);
            ot[(r * 16 + (l >> 4) * 4 + j) * 65 + (w * 16 + (l & 15))] = v;
        }
    }
    __syncthreads();

    if (F32OUT) {
        const int r = tid >> 2, c0 = (tid & 3) * 16;
        float* dst = (float*)outSM + (size_t)b * smB + smOff +
                     (size_t)(m0 + r) * ldsm + n0 + c0;
#pragma unroll
        for (int k = 0; k < 4; ++k) {
            float4 v;
            v.x = ot[r * 65 + c0 + 4 * k + 0];
            v.y = ot[r * 65 + c0 + 4 * k + 1];
            v.z = ot[r * 65 + c0 + 4 * k + 2];
            v.w = ot[r * 65 + c0 + 4 * k + 3];
            *(float4*)(dst + 4 * k) = v;
        }
    } else {
        const int r = tid >> 2, c0 = (tid & 3) * 16;
        float sc = 1.f;
        if (EPI == 2) sc = 0.5f * dinv[(size_t)b * Nc + m0 + r];
        u16x8 o1, o2;
#pragma unroll
        for (int j = 0; j < 8; ++j) {
            float v = ot[r * 65 + c0 + j];
            if (EPI == 2) v *= sc;
            o1[j] = f2bf(v);
        }
#pragma unroll
        for (int j = 0; j < 8; ++j) {
            float v = ot[r * 65 + c0 + 8 + j];
            if (EPI == 2) v *= sc;
            o2[j] = f2bf(v);
        }
        unsigned short* dst = outSM + (size_t)b * smB + smOff +
                              (size_t)(m0 + r) * ldsm + n0 + c0;
        *(u16x8*)dst = o1;
        *(u16x8*)(dst + 8) = o2;
    }

    if (CMOUT) {
        const int c = tid >> 2, r0 = (tid & 3) * 16;
        const float* dv = dinv + (size_t)b * Nc + m0 + r0;
        u16x8 o1, o2;
#pragma unroll
        for (int j = 0; j < 8; ++j) {
            float v = ot[(r0 + j) * 65 + c];
            if (CMOUT == 2) v *= dv[j];
            o1[j] = f2bf(v);
        }
#pragma unroll
        for (int j = 0; j < 8; ++j) {
            float v = ot[(r0 + 8 + j) * 65 + c];
            if (CMOUT == 2) v *= dv[8 + j];
            o2[j] = f2bf(v);
        }
        unsigned short* dst = outCM + (size_t)b * cmB + (size_t)(n0 + c) * Nc + m0 + r0;
        *(u16x8*)dst = o1;
        *(u16x8*)(dst + 8) = o2;
    }

    if (BNSTAT) {
        float* p1 = (float*)(lds + 16896);
        float* p2 = p1 + 256;
        const int col = tid & 63, rq = tid >> 6;
        float s = 0.f, s2 = 0.f;
#pragma unroll
        for (int i = 0; i < 16; ++i) {
            float v = ot[(rq * 16 + i) * 65 + col];
            s += v;
            if (BNSTAT == 2) s2 = fmaf(v, v, s2);
        }
        p1[rq * 64 + col] = s;
        if (BNSTAT == 2) p2[rq * 64 + col] = s2;
        __syncthreads();
        if (tid < 64) {
            float a = 0.f, a2 = 0.f;
#pragma unroll
            for (int q = 0; q < 4; ++q) {
                a += p1[q * 64 + tid];
                if (BNSTAT == 2) a2 += p2[q * 64 + tid];
            }
            size_t slot = ((size_t)b * 49 + blockIdx.y) * 256 + n0 + tid;
            ps[slot] = a;
            if (BNSTAT == 2) ps2[slot] = a2;
        }
    }
}

// ---------------------------------------------------------------------------
// weights f32 -> bf16 (Wt+Wp concatenated into Wcomb[256][256])
// ---------------------------------------------------------------------------
__global__ __launch_bounds__(256) void cvtw_k(
    const float* __restrict__ Wt, const float* __restrict__ Wp,
    const float* __restrict__ Wg, const float* __restrict__ W1,
    const float* __restrict__ W2,
    unsigned short* __restrict__ Wcomb, unsigned short* __restrict__ Wgh,
    unsigned short* __restrict__ W1h, unsigned short* __restrict__ W2h)
{
    size_t e = ((size_t)blockIdx.x * 256 + threadIdx.x) * 4;
    const float* src; unsigned short* dst;
    if (e < 32768)            { src = Wt + e;                    dst = Wcomb + e; }
    else if (e < 65536)       { src = Wp + (e - 32768);          dst = Wcomb + e; }
    else if (e < 65536 + 163840)     { size_t o = e - 65536;          src = Wg + o; dst = Wgh + o; }
    else if (e < 65536 + 2 * 163840) { size_t o = e - 65536 - 163840; src = W1 + o; dst = W1h + o; }
    else                             { size_t o = e - 65536 - 327680; src = W2 + o; dst = W2h + o; }
    float4 v = *(const float4*)src;
    u16x4 t;
    t[0] = f2bf(v.x); t[1] = f2bf(v.y); t[2] = f2bf(v.z); t[3] = f2bf(v.w);
    *(u16x4*)dst = t;
}

// x[b][c][n] f32 -> out_sm[b][n][c] f32 + outh bf16
__global__ __launch_bounds__(256) void xpin_k(
    const float* __restrict__ x, float* __restrict__ out_sm,
    unsigned short* __restrict__ outh)
{
    __shared__ float tb[64][65];
    int b = blockIdx.z, c0 = blockIdx.y * 64, n0 = blockIdx.x * 64;
    int t = threadIdx.x;
    {
        int ci = t >> 2, nb = (t & 3) * 16;
        const float* src = x + ((size_t)b * Cc + c0 + ci) * Nc + n0 + nb;
#pragma unroll
        for (int k = 0; k < 4; ++k) {
            float4 v = *(const float4*)(src + 4 * k);
            tb[ci][nb + 4 * k + 0] = v.x; tb[ci][nb + 4 * k + 1] = v.y;
            tb[ci][nb + 4 * k + 2] = v.z; tb[ci][nb + 4 * k + 3] = v.w;
        }
    }
    __syncthreads();
    {
        int r = t >> 2, cb = (t & 3) * 16;
        size_t off = ((size_t)b * Nc + n0 + r) * Cc + c0 + cb;
        float vv[16];
#pragma unroll
        for (int j = 0; j < 16; ++j) vv[j] = tb[cb + j][r];
        float* dst = out_sm + off;
#pragma unroll
        for (int k = 0; k < 4; ++k) {
            float4 v; v.x = vv[4*k]; v.y = vv[4*k+1]; v.z = vv[4*k+2]; v.w = vv[4*k+3];
            *(float4*)(dst + 4 * k) = v;
        }
        u16x8 h1, h2;
#pragma unroll
        for (int j = 0; j < 8; ++j) { h1[j] = f2bf(vv[j]); h2[j] = f2bf(vv[8 + j]); }
        unsigned short* dh = outh + off;
        *(u16x8*)dh = h1;
        *(u16x8*)(dh + 8) = h2;
    }
}

// out_sm[b][n][c] f32 -> d_out[b][c][n] f32
__global__ __launch_bounds__(256) void xpout_k(
    const float* __restrict__ out_sm, float* __restrict__ outp)
{
    __shared__ float tb[64][65];
    int b = blockIdx.z, c0 = blockIdx.y * 64, n0 = blockIdx.x * 64;
    int t = threadIdx.x;
    {
        int r = t >> 2, cb = (t & 3) * 16;
        const float* src = out_sm + ((size_t)b * Nc + n0 + r) * Cc + c0 + cb;
#pragma unroll
        for (int k = 0; k < 4; ++k) {
            float4 v = *(const float4*)(src + 4 * k);
            tb[r][cb + 4 * k + 0] = v.x; tb[r][cb + 4 * k + 1] = v.y;
            tb[r][cb + 4 * k + 2] = v.z; tb[r][cb + 4 * k + 3] = v.w;
        }
    }
    __syncthreads();
    {
        int c = t >> 2, rb = (t & 3) * 16;
        float vv[16];
#pragma unroll
        for (int j = 0; j < 16; ++j) vv[j] = tb[rb + j][c];
        float* dst = outp + ((size_t)b * Cc + c0 + c) * Nc + n0 + rb;
#pragma unroll
        for (int k = 0; k < 4; ++k) {
            float4 v; v.x = vv[4*k]; v.y = vv[4*k+1]; v.z = vv[4*k+2]; v.w = vv[4*k+3];
            *(float4*)(dst + 4 * k) = v;
        }
    }
}

// dinv[b][i] = d>0 ? rsqrt(d) : 0, d = 0.5 * sum_q U_sm[b][i][q] * rs[b][q^128]
__global__ __launch_bounds__(256) void dinv_k(
    const unsigned short* __restrict__ U, const float* __restrict__ rp,
    float* __restrict__ dinv)
{
    __shared__ float rsl[256];
    int b = blockIdx.y, tid = threadIdx.x;
    float s = 0.f;
    for (int j = 0; j < 49; ++j) s += rp[((size_t)b * 49 + j) * 256 + tid];
    rsl[tid ^ 128] = s;
    __syncthreads();
    int i = blockIdx.x * 256 + tid;
    if (i < Nc) {
        const unsigned short* row = U + ((size_t)b * Nc + i) * 256;
        float acc = 0.f;
        for (int q0 = 0; q0 < 256; q0 += 8) {
            u16x8 v = *(const u16x8*)(row + q0);
#pragma unroll
            for (int j = 0; j < 8; ++j) acc = fmaf(bf2f(v[j]), rsl[q0 + j], acc);
        }
        float d = 0.5f * acc;
        dinv[(size_t)b * Nc + i] = d > 0.f ? rsqrtf(d) : 0.f;
    }
}

// MstT[b][p][q] = sum_ks Cpart_f32[ks][b][p][q^128]  -> bf16
__global__ __launch_bounds__(256) void redmst_k(
    const float* __restrict__ Cpart, unsigned short* __restrict__ MstT)
{
    int e8 = blockIdx.x * 256 + threadIdx.x;    // 16384 total
    int bp = e8 >> 5, qc = e8 & 31;
    size_t dstOff = ((size_t)bp * 32 + qc) * 8;
    size_t srcOff = ((size_t)bp * 32 + (qc ^ 16)) * 8;
    float4 s0 = {0.f, 0.f, 0.f, 0.f}, s1 = {0.f, 0.f, 0.f, 0.f};
    for (int ks = 0; ks < KSn; ++ks) {
        const float* base = Cpart + (size_t)ks * (Bc * Pc * Cc) + srcOff;
        float4 v0 = *(const float4*)base;
        float4 v1 = *(const float4*)(base + 4);
        s0.x += v0.x; s0.y += v0.y; s0.z += v0.z; s0.w += v0.w;
        s1.x += v1.x; s1.y += v1.y; s1.z += v1.z; s1.w += v1.w;
    }
    u16x8 o;
    o[0] = f2bf(s0.x); o[1] = f2bf(s0.y); o[2] = f2bf(s0.z); o[3] = f2bf(s0.w);
    o[4] = f2bf(s1.x); o[5] = f2bf(s1.y); o[6] = f2bf(s1.z); o[7] = f2bf(s1.w);
    *(u16x8*)(MstT + dstOff) = o;
}

__global__ __launch_bounds__(256) void bnfin_k(
    const float* __restrict__ ps, const float* __restrict__ ps2,
    const float* __restrict__ gamma, const float* __restrict__ beta,
    float* __restrict__ scale, float* __restrict__ shift)
{
    int c = threadIdx.x;
    float a = 0.f, a2 = 0.f;
    for (int g = 0; g < 196; ++g) {
        a += ps[(size_t)g * 256 + c];
        a2 += ps2[(size_t)g * 256 + c];
    }
    const float inv = 1.f / (float)(Bc * Nc);
    float mean = a * inv;
    float var = a2 * inv - mean * mean;
    float sc = gamma[c] * rsqrtf(var + EPSc);
    scale[c] = sc;
    shift[c] = beta[c] - mean * sc;
}

// out_sm += BN(o); outh = bf16(out_sm)
__global__ __launch_bounds__(256) void bnapp_k(
    const unsigned short* __restrict__ o, const float* __restrict__ scale,
    const float* __restrict__ shift, float* __restrict__ out_sm,
    unsigned short* __restrict__ outh)
{
    __shared__ float lsc[256], lsh[256];
    int t = threadIdx.x;
    lsc[t] = scale[t];
    lsh[t] = shift[t];
    __syncthreads();
    size_t e = ((size_t)blockIdx.x * 256 + t) * 8;
    int c8 = (int)(e & 255);
    u16x8 ov = *(const u16x8*)(o + e);
    float* op = out_sm + e;
    float4 o1 = *(float4*)op, o2 = *(float4*)(op + 4);
    float r[8];
#pragma unroll
    for (int j = 0; j < 8; ++j) r[j] = fmaf(bf2f(ov[j]), lsc[c8 + j], lsh[c8 + j]);
    o1.x += r[0]; o1.y += r[1]; o1.z += r[2]; o1.w += r[3];
    o2.x += r[4]; o2.y += r[5]; o2.z += r[6]; o2.w += r[7];
    *(float4*)op = o1;
    *(float4*)(op + 4) = o2;
    u16x8 hv;
    hv[0] = f2bf(o1.x); hv[1] = f2bf(o1.y); hv[2] = f2bf(o1.z); hv[3] = f2bf(o1.w);
    hv[4] = f2bf(o2.x); hv[5] = f2bf(o2.y); hv[6] = f2bf(o2.z); hv[7] = f2bf(o2.w);
    *(u16x8*)(outh + e) = hv;
}

}  // namespace

extern "C" void kernel_launch(void* const* d_in, const int* in_sizes, int n_in,
                              void* d_out, int out_size, void* d_ws, size_t ws_size,
                              hipStream_t stream) {
    const float* x     = (const float*)d_in[0];
    const float* Wt    = (const float*)d_in[1];
    const float* Wp    = (const float*)d_in[2];
    const float* Wg    = (const float*)d_in[3];
    const float* W1    = (const float*)d_in[4];
    const float* W2    = (const float*)d_in[5];
    const float* gamma = (const float*)d_in[6];
    const float* beta  = (const float*)d_in[7];

    char* p = (char*)d_ws;
    auto alloc = [&](size_t bytes) { char* r = p; p += (bytes + 255) & ~(size_t)255; return r; };
    float*          out_sm = (float*)         alloc((size_t)Bc * Nc * Cc * 4);
    unsigned short* outh   = (unsigned short*)alloc((size_t)Bc * Nc * Cc * 2);
    unsigned short* U_sm   = (unsigned short*)alloc((size_t)Bc * Nc * 256 * 2);
    unsigned short* U_cm   = (unsigned short*)alloc((size_t)Bc * 256 * Nc * 2);
    unsigned short* g_sm   = (unsigned short*)alloc((size_t)Bc * Nc * Pc * 2);
    unsigned short* g_cmd  = (unsigned short*)alloc((size_t)Bc * Pc * Nc * 2);
    unsigned short* ag_sm  = (unsigned short*)alloc((size_t)Bc * Nc * Pc * 2);
    unsigned short* o_sm   = (unsigned short*)alloc((size_t)Bc * Nc * Cc * 2);
    float*          Cpart  = (float*)         alloc((size_t)KSn * Bc * Pc * Cc * 4);
    unsigned short* MstT   = (unsigned short*)alloc((size_t)Bc * Pc * Cc * 2);
    unsigned short* Wcomb  = (unsigned short*)alloc((size_t)Cc * Cc * 2);
    unsigned short* Wgh    = (unsigned short*)alloc((size_t)Sc * Pc * Cc * 2);
    unsigned short* W1h    = (unsigned short*)alloc((size_t)Sc * Cc * Pc * 2);
    unsigned short* W2h    = (unsigned short*)alloc((size_t)Sc * Cc * Pc * 2);
    float*          rp     = (float*)         alloc((size_t)Bc * 49 * 256 * 4);
    float*          dinv   = (float*)         alloc((size_t)Bc * Nc * 4);
    float*          ps     = (float*)         alloc((size_t)196 * 256 * 4);
    float*          ps2    = (float*)         alloc((size_t)196 * 256 * 4);
    float*          scale  = (float*)         alloc(256 * 4);
    float*          shiftb = (float*)         alloc(256 * 4);

    const long NC256 = (long)Nc * 256;
    const long NC128 = (long)Nc * 128;
    dim3 blk(256);

    cvtw_k<<<544, blk, 0, stream>>>(Wt, Wp, Wg, W1, W2, Wcomb, Wgh, W1h, W2h);
    xpin_k<<<dim3(49, 4, Bc), blk, 0, stream>>>(x, out_sm, outh);

    // U = relu([Wt;Wp] @ x): spatial-major + column-major + column partial sums
    mgemm<1, false, 1, false, 1, false><<<dim3(4, 49, Bc), blk, 0, stream>>>(
        outh, 256, NC256, Wcomb, 256, 0, nullptr, nullptr,
        U_sm, 256, NC256, 0, U_cm, (long)256 * Nc, rp, nullptr, 256, 0, nullptr);

    dinv_k<<<dim3(13, Bc), blk, 0, stream>>>(U_sm, rp, dinv);

    for (int s = 0; s < Sc; ++s) {
        // g = Wg[s] @ out; also g_cmd[p][i] = g * dinv[i] (channel-major)
        mgemm<0, false, 2, false, 0, false><<<dim3(2, 49, Bc), blk, 0, stream>>>(
            outh, 256, NC256, Wgh + (size_t)s * Pc * Cc, 256, 0, nullptr, nullptr,
            g_sm, 128, NC128, 0, g_cmd, (long)Pc * Nc, nullptr, nullptr, 256, 0, dinv);
        // Cpart[ks][p][q] = partial_i g_cmd[p][i] * U_cm[q][i]   (f32 partials)
        mgemm<0, false, 0, true, 0, true><<<dim3(4, 2, KSn * Bc), blk, 0, stream>>>(
            g_cmd, Nc, (long)Pc * Nc, U_cm, Nc, (long)256 * Nc, nullptr, nullptr,
            (unsigned short*)Cpart, 256, (long)Pc * Cc, (long)Bc * Pc * Cc,
            nullptr, 0, nullptr, nullptr, Nc, KCH, nullptr);
        redmst_k<<<64, blk, 0, stream>>>(Cpart, MstT);
        // ag[n][p'] = 0.5*dinv[n] * sum_q U_sm[n][q] * MstT[p'][q]
        mgemm<2, false, 0, false, 0, false><<<dim3(2, 49, Bc), blk, 0, stream>>>(
            U_sm, 256, NC256, MstT, 256, (long)Pc * Cc, nullptr, nullptr,
            ag_sm, 128, NC128, 0, nullptr, 0, nullptr, nullptr, 256, 0, dinv);
        // o = W1[s] @ ag + W2[s] @ g  + fused BN partial stats
        mgemm<0, true, 0, false, 2, false><<<dim3(4, 49, Bc), blk, 0, stream>>>(
            ag_sm, 128, NC128, W1h + (size_t)s * Cc * Pc, 128, 0,
            g_sm, W2h + (size_t)s * Cc * Pc,
            o_sm, 256, NC256, 0, nullptr, 0, ps, ps2, 128, 0, nullptr);
        bnfin_k<<<1, blk, 0, stream>>>(ps, ps2, gamma + s * Cc, beta + s * Cc,
                                       scale, shiftb);
        bnapp_k<<<1568, blk, 0, stream>>>(o_sm, scale, shiftb, out_sm, outh);
    }

    xpout_k<<<dim3(49, 4, Bc), blk, 0, stream>>>(out_sm, (float*)d_out);
}

// Round 4
// 280.028 us; speedup vs baseline: 2.5589x; 1.0738x over previous
//
#include <hip/hip_runtime.h>

namespace {

constexpr int Bc = 4;
constexpr int Cc = 256;
constexpr int Pc = 128;
constexpr int Nc = 3136;   // 56*56 = 49*64
constexpr int Sc = 5;
constexpr int KSn = 7;     // split-K chunks for abt (3136 = 7*448)
constexpr int KCH = 448;
constexpr float EPSc = 1e-5f;

typedef __attribute__((ext_vector_type(8))) short bf16x8;
typedef __attribute__((ext_vector_type(4))) float f32x4;
typedef __attribute__((ext_vector_type(8))) unsigned short u16x8;
typedef __attribute__((ext_vector_type(4))) unsigned short u16x4;

__device__ inline float bf2f(unsigned short u) {
    return __uint_as_float(((unsigned)u) << 16);
}
__device__ inline unsigned short f2bf(float f) {
    unsigned u = __float_as_uint(f);
    return (unsigned short)((u + 0x7FFFu + ((u >> 16) & 1u)) >> 16);
}

// ---------------------------------------------------------------------------
// MFMA GEMM: D[m][n] = sum_k A[m][k] * B[n][k]   (both operands K-contiguous)
//   tile 64(m) x 128(n), 4 waves (each 64x32), K-step 64, double-buffered LDS
//   via global_load_lds(16B), granule swizzle phys = g ^ (row&7).
// EPI:    0 none, 1 relu (applied to all outputs), 2 scale rows by 0.5*dinv[m]
// CMOUT:  0 none, 1 plain column-major copy, 2 column-major scaled by dinv[m]
// SPLITK: z = ks*Bc+b, k range [ks*kchunk, +kchunk), out offset ks*smSlice
// BNSTAT: 0 none, 1 column sums -> ps, 2 column sums+sumsq -> ps,ps2
// F32OUT: write f32 output (outSM reinterpreted as float*)
// ---------------------------------------------------------------------------
template <int EPI, int CMOUT, bool SPLITK, int BNSTAT, bool F32OUT>
__global__ __launch_bounds__(256) void mgemm(
    const unsigned short* __restrict__ A, int lda, long aB,
    const unsigned short* __restrict__ Bw, int ldb, long bB,
    unsigned short* __restrict__ outSM, int ldsm, long smB, long smSlice,
    unsigned short* __restrict__ outCM, long cmB,
    float* __restrict__ ps, float* __restrict__ ps2,
    int K, int kchunk, const float* __restrict__ dinv)
{
    constexpr int TBA = 64 * 64 * 2;     // 8192  A tile bytes
    constexpr int TBB = 128 * 64 * 2;    // 16384 B tile bytes
    constexpr int BUF = TBA + TBB;       // 24576
    __shared__ __align__(16) char lds[2 * BUF];

    int b, kstart, kend;
    long smOff;
    if (SPLITK) {
        b = blockIdx.z & 3;
        int ks = blockIdx.z >> 2;
        kstart = ks * kchunk;
        kend = kstart + kchunk;
        smOff = (long)ks * smSlice;
    } else {
        b = blockIdx.z; kstart = 0; kend = K; smOff = 0;
    }
    const int n0 = blockIdx.x * 128;
    const int m0 = blockIdx.y * 64;
    const int tid = threadIdx.x;
    const int w = tid >> 6, l = tid & 63;

    const unsigned short* Ab = A + (size_t)b * aB + (size_t)m0 * lda;
    const unsigned short* Bb = Bw + (size_t)b * bB + (size_t)n0 * ldb;

    // staging: lane l of wave w -> local row w*8 + (l>>3), swizzled granule
    const int srow = w * 8 + (l >> 3);               // 0..31
    const int gsw = ((l & 7) ^ (l >> 3)) * 8;        // swizzled source granule

    f32x4 acc[4][2] = {};

    auto stage = [&](int buf, int k0) {
        char* base = lds + buf * BUF;
#pragma unroll
        for (int j = 0; j < 2; ++j) {
            __builtin_amdgcn_global_load_lds(
                (const __attribute__((address_space(1))) void*)
                    (Ab + (size_t)(j * 32 + srow) * lda + k0 + gsw),
                (__attribute__((address_space(3))) void*)(base + j * 4096 + w * 1024),
                16, 0, 0);
        }
#pragma unroll
        for (int j = 0; j < 4; ++j) {
            __builtin_amdgcn_global_load_lds(
                (const __attribute__((address_space(1))) void*)
                    (Bb + (size_t)(j * 32 + srow) * ldb + k0 + gsw),
                (__attribute__((address_space(3))) void*)(base + TBA + j * 4096 + w * 1024),
                16, 0, 0);
        }
    };

    auto compute = [&](int buf) {
        const char* base = lds + buf * BUF;
        const int lo = l & 15, gq = l >> 4;
#pragma unroll
        for (int kh = 0; kh < 2; ++kh) {
            const int lg = kh * 4 + gq;
            bf16x8 bf[2];
#pragma unroll
            for (int c = 0; c < 2; ++c) {
                int brow = w * 32 + c * 16 + lo;
                bf[c] = *(const bf16x8*)(base + TBA + brow * 128 + ((lg ^ (brow & 7)) << 4));
            }
#pragma unroll
            for (int r = 0; r < 4; ++r) {
                int row = r * 16 + lo;
                bf16x8 af = *(const bf16x8*)(base + row * 128 + ((lg ^ (row & 7)) << 4));
                acc[r][0] = __builtin_amdgcn_mfma_f32_16x16x32_bf16(af, bf[0], acc[r][0], 0, 0, 0);
                acc[r][1] = __builtin_amdgcn_mfma_f32_16x16x32_bf16(af, bf[1], acc[r][1], 0, 0, 0);
            }
        }
    };

    stage(0, kstart);
    __syncthreads();
    const int nst = (kend - kstart) >> 6;
    for (int s = 0; s < nst; ++s) {
        if (s + 1 < nst) stage((s + 1) & 1, kstart + ((s + 1) << 6));
        compute(s & 1);
        __syncthreads();
    }

    // stage accumulators to LDS f32 [64][132]
    float* ot = (float*)lds;
    {
        const int lo = l & 15, gq = l >> 4;
#pragma unroll
        for (int r = 0; r < 4; ++r)
#pragma unroll
            for (int c = 0; c < 2; ++c)
#pragma unroll
                for (int j = 0; j < 4; ++j) {
                    float v = acc[r][c][j];
                    if (EPI == 1) v = fmaxf(v, 0.f);
                    ot[(r * 16 + gq * 4 + j) * 132 + w * 32 + c * 16 + lo] = v;
                }
    }
    __syncthreads();

    {   // row-major store: thread -> row tid>>2, cols (tid&3)*32..+32
        const int r = tid >> 2, c0 = (tid & 3) * 32;
        if (F32OUT) {
            float* dst = (float*)outSM + (size_t)b * smB + smOff +
                         (size_t)(m0 + r) * ldsm + n0 + c0;
#pragma unroll
            for (int k = 0; k < 8; ++k) {
                float4 v;
                v.x = ot[r * 132 + c0 + 4 * k + 0];
                v.y = ot[r * 132 + c0 + 4 * k + 1];
                v.z = ot[r * 132 + c0 + 4 * k + 2];
                v.w = ot[r * 132 + c0 + 4 * k + 3];
                *(float4*)(dst + 4 * k) = v;
            }
        } else {
            float sc = 1.f;
            if (EPI == 2) sc = 0.5f * dinv[(size_t)b * Nc + m0 + r];
            unsigned short* dst = outSM + (size_t)b * smB + smOff +
                                  (size_t)(m0 + r) * ldsm + n0 + c0;
#pragma unroll
            for (int k = 0; k < 4; ++k) {
                u16x8 o;
#pragma unroll
                for (int j = 0; j < 8; ++j) {
                    float v = ot[r * 132 + c0 + 8 * k + j];
                    if (EPI == 2) v *= sc;
                    o[j] = f2bf(v);
                }
                *(u16x8*)(dst + 8 * k) = o;
            }
        }
    }

    if (CMOUT) {   // column-major store: thread -> col tid>>1, rows (tid&1)*32..+32
        const int c = tid >> 1, r0 = (tid & 1) * 32;
        const float* dv = dinv + (size_t)b * Nc + m0 + r0;
        unsigned short* dst = outCM + (size_t)b * cmB + (size_t)(n0 + c) * Nc + m0 + r0;
#pragma unroll
        for (int k = 0; k < 4; ++k) {
            u16x8 o;
#pragma unroll
            for (int j = 0; j < 8; ++j) {
                float v = ot[(r0 + 8 * k + j) * 132 + c];
                if (CMOUT == 2) v *= dv[8 * k + j];
                o[j] = f2bf(v);
            }
            *(u16x8*)(dst + 8 * k) = o;
        }
    }

    if (BNSTAT) {
        float* p1 = (float*)(lds + 35840);
        float* p2 = p1 + 256;
        const int col = tid & 127, half = tid >> 7;
        float s = 0.f, s2 = 0.f;
#pragma unroll
        for (int i = 0; i < 32; ++i) {
            float v = ot[(half * 32 + i) * 132 + col];
            s += v;
            if (BNSTAT == 2) s2 = fmaf(v, v, s2);
        }
        p1[half * 128 + col] = s;
        if (BNSTAT == 2) p2[half * 128 + col] = s2;
        __syncthreads();
        if (tid < 128) {
            float a = p1[tid] + p1[128 + tid];
            size_t slot = ((size_t)b * 49 + blockIdx.y) * 256 + n0 + tid;
            ps[slot] = a;
            if (BNSTAT == 2) ps2[slot] = p2[tid] + p2[128 + tid];
        }
    }
}

// ---------------------------------------------------------------------------
// weights f32 -> bf16; Wt+Wp -> Wcomb[256][256]; W1,W2 interleaved -> Wcat
// ---------------------------------------------------------------------------
__global__ __launch_bounds__(256) void cvtw_k(
    const float* __restrict__ Wt, const float* __restrict__ Wp,
    const float* __restrict__ Wg, const float* __restrict__ W1,
    const float* __restrict__ W2,
    unsigned short* __restrict__ Wcomb, unsigned short* __restrict__ Wgh,
    unsigned short* __restrict__ Wcat)
{
    size_t e = ((size_t)blockIdx.x * 256 + threadIdx.x) * 4;
    const float* src; unsigned short* dst;
    if (e < 32768)      { src = Wt + e;           dst = Wcomb + e; }
    else if (e < 65536) { src = Wp + (e - 32768); dst = Wcomb + e; }
    else if (e < 65536 + 163840) {
        size_t o = e - 65536; src = Wg + o; dst = Wgh + o;
    } else if (e < 65536 + 2 * 163840) {
        size_t o = e - 65536 - 163840; src = W1 + o;
        dst = Wcat + ((o >> 7) << 8) + (o & 127);
    } else {
        size_t o = e - 65536 - 327680; src = W2 + o;
        dst = Wcat + ((o >> 7) << 8) + 128 + (o & 127);
    }
    float4 v = *(const float4*)src;
    u16x4 t;
    t[0] = f2bf(v.x); t[1] = f2bf(v.y); t[2] = f2bf(v.z); t[3] = f2bf(v.w);
    *(u16x4*)dst = t;
}

// x[b][c][n] f32 -> out_sm[b][n][c] f32 + outh bf16
__global__ __launch_bounds__(256) void xpin_k(
    const float* __restrict__ x, float* __restrict__ out_sm,
    unsigned short* __restrict__ outh)
{
    __shared__ float tb[64][65];
    int b = blockIdx.z, c0 = blockIdx.y * 64, n0 = blockIdx.x * 64;
    int t = threadIdx.x;
    {
        int ci = t >> 2, nb = (t & 3) * 16;
        const float* src = x + ((size_t)b * Cc + c0 + ci) * Nc + n0 + nb;
#pragma unroll
        for (int k = 0; k < 4; ++k) {
            float4 v = *(const float4*)(src + 4 * k);
            tb[ci][nb + 4 * k + 0] = v.x; tb[ci][nb + 4 * k + 1] = v.y;
            tb[ci][nb + 4 * k + 2] = v.z; tb[ci][nb + 4 * k + 3] = v.w;
        }
    }
    __syncthreads();
    {
        int r = t >> 2, cb = (t & 3) * 16;
        size_t off = ((size_t)b * Nc + n0 + r) * Cc + c0 + cb;
        float vv[16];
#pragma unroll
        for (int j = 0; j < 16; ++j) vv[j] = tb[cb + j][r];
        float* dst = out_sm + off;
#pragma unroll
        for (int k = 0; k < 4; ++k) {
            float4 v; v.x = vv[4*k]; v.y = vv[4*k+1]; v.z = vv[4*k+2]; v.w = vv[4*k+3];
            *(float4*)(dst + 4 * k) = v;
        }
        u16x8 h1, h2;
#pragma unroll
        for (int j = 0; j < 8; ++j) { h1[j] = f2bf(vv[j]); h2[j] = f2bf(vv[8 + j]); }
        unsigned short* dh = outh + off;
        *(u16x8*)dh = h1;
        *(u16x8*)(dh + 8) = h2;
    }
}

// out_sm[b][n][c] f32 -> d_out[b][c][n] f32
__global__ __launch_bounds__(256) void xpout_k(
    const float* __restrict__ out_sm, float* __restrict__ outp)
{
    __shared__ float tb[64][65];
    int b = blockIdx.z, c0 = blockIdx.y * 64, n0 = blockIdx.x * 64;
    int t = threadIdx.x;
    {
        int r = t >> 2, cb = (t & 3) * 16;
        const float* src = out_sm + ((size_t)b * Nc + n0 + r) * Cc + c0 + cb;
#pragma unroll
        for (int k = 0; k < 4; ++k) {
            float4 v = *(const float4*)(src + 4 * k);
            tb[r][cb + 4 * k + 0] = v.x; tb[r][cb + 4 * k + 1] = v.y;
            tb[r][cb + 4 * k + 2] = v.z; tb[r][cb + 4 * k + 3] = v.w;
        }
    }
    __syncthreads();
    {
        int c = t >> 2, rb = (t & 3) * 16;
        float vv[16];
#pragma unroll
        for (int j = 0; j < 16; ++j) vv[j] = tb[rb + j][c];
        float* dst = outp + ((size_t)b * Cc + c0 + c) * Nc + n0 + rb;
#pragma unroll
        for (int k = 0; k < 4; ++k) {
            float4 v; v.x = vv[4*k]; v.y = vv[4*k+1]; v.z = vv[4*k+2]; v.w = vv[4*k+3];
            *(float4*)(dst + 4 * k) = v;
        }
    }
}

// dinv[b][i] = d>0 ? rsqrt(d) : 0, d = 0.5 * sum_q U_sm[b][i][q] * rs[b][q^128]
__global__ __launch_bounds__(256) void dinv_k(
    const unsigned short* __restrict__ U, const float* __restrict__ rp,
    float* __restrict__ dinv)
{
    __shared__ float rsl[256];
    int b = blockIdx.y, tid = threadIdx.x;
    float s = 0.f;
    for (int j = 0; j < 49; ++j) s += rp[((size_t)b * 49 + j) * 256 + tid];
    rsl[tid ^ 128] = s;
    __syncthreads();
    int i = blockIdx.x * 256 + tid;
    if (i < Nc) {
        const unsigned short* row = U + ((size_t)b * Nc + i) * 256;
        float acc = 0.f;
        for (int q0 = 0; q0 < 256; q0 += 8) {
            u16x8 v = *(const u16x8*)(row + q0);
#pragma unroll
            for (int j = 0; j < 8; ++j) acc = fmaf(bf2f(v[j]), rsl[q0 + j], acc);
        }
        float d = 0.5f * acc;
        dinv[(size_t)b * Nc + i] = d > 0.f ? rsqrtf(d) : 0.f;
    }
}

// MstT[b][p][q] = sum_ks Cpart_f32[ks][b][p][q^128]  -> bf16
__global__ __launch_bounds__(256) void redmst_k(
    const float* __restrict__ Cpart, unsigned short* __restrict__ MstT)
{
    int e8 = blockIdx.x * 256 + threadIdx.x;    // 16384 total
    int bp = e8 >> 5, qc = e8 & 31;
    size_t dstOff = ((size_t)bp * 32 + qc) * 8;
    size_t srcOff = ((size_t)bp * 32 + (qc ^ 16)) * 8;
    float4 s0 = {0.f, 0.f, 0.f, 0.f}, s1 = {0.f, 0.f, 0.f, 0.f};
    for (int ks = 0; ks < KSn; ++ks) {
        const float* base = Cpart + (size_t)ks * (Bc * Pc * Cc) + srcOff;
        float4 v0 = *(const float4*)base;
        float4 v1 = *(const float4*)(base + 4);
        s0.x += v0.x; s0.y += v0.y; s0.z += v0.z; s0.w += v0.w;
        s1.x += v1.x; s1.y += v1.y; s1.z += v1.z; s1.w += v1.w;
    }
    u16x8 o;
    o[0] = f2bf(s0.x); o[1] = f2bf(s0.y); o[2] = f2bf(s0.z); o[3] = f2bf(s0.w);
    o[4] = f2bf(s1.x); o[5] = f2bf(s1.y); o[6] = f2bf(s1.z); o[7] = f2bf(s1.w);
    *(u16x8*)(MstT + dstOff) = o;
}

// parallel BN finalize: 16 blocks x 16 channels
__global__ __launch_bounds__(256) void bnfin_k(
    const float* __restrict__ ps, const float* __restrict__ ps2,
    const float* __restrict__ gamma, const float* __restrict__ beta,
    float* __restrict__ scale, float* __restrict__ shift)
{
    __shared__ float l1[256], l2[256];
    int t = threadIdx.x;
    int c = blockIdx.x * 16 + (t & 15);
    int gl = t >> 4;
    float a = 0.f, a2 = 0.f;
    for (int g = gl; g < 196; g += 16) {
        a += ps[(size_t)g * 256 + c];
        a2 += ps2[(size_t)g * 256 + c];
    }
    l1[t] = a; l2[t] = a2;
    __syncthreads();
    if (gl == 0) {
#pragma unroll
        for (int j = 1; j < 16; ++j) {
            a += l1[j * 16 + (t & 15)];
            a2 += l2[j * 16 + (t & 15)];
        }
        const float inv = 1.f / (float)(Bc * Nc);
        float mean = a * inv;
        float var = a2 * inv - mean * mean;
        float sc = gamma[c] * rsqrtf(var + EPSc);
        scale[c] = sc;
        shift[c] = beta[c] - mean * sc;
    }
}

// out_sm += BN(o); outh = bf16(out_sm)
__global__ __launch_bounds__(256) void bnapp_k(
    const unsigned short* __restrict__ o, const float* __restrict__ scale,
    const float* __restrict__ shift, float* __restrict__ out_sm,
    unsigned short* __restrict__ outh)
{
    __shared__ float lsc[256], lsh[256];
    int t = threadIdx.x;
    lsc[t] = scale[t];
    lsh[t] = shift[t];
    __syncthreads();
    size_t e = ((size_t)blockIdx.x * 256 + t) * 8;
    int c8 = (int)(e & 255);
    u16x8 ov = *(const u16x8*)(o + e);
    float* op = out_sm + e;
    float4 o1 = *(float4*)op, o2 = *(float4*)(op + 4);
    float r[8];
#pragma unroll
    for (int j = 0; j < 8; ++j) r[j] = fmaf(bf2f(ov[j]), lsc[c8 + j], lsh[c8 + j]);
    o1.x += r[0]; o1.y += r[1]; o1.z += r[2]; o1.w += r[3];
    o2.x += r[4]; o2.y += r[5]; o2.z += r[6]; o2.w += r[7];
    *(float4*)op = o1;
    *(float4*)(op + 4) = o2;
    u16x8 hv;
    hv[0] = f2bf(o1.x); hv[1] = f2bf(o1.y); hv[2] = f2bf(o1.z); hv[3] = f2bf(o1.w);
    hv[4] = f2bf(o2.x); hv[5] = f2bf(o2.y); hv[6] = f2bf(o2.z); hv[7] = f2bf(o2.w);
    *(u16x8*)(outh + e) = hv;
}

}  // namespace

extern "C" void kernel_launch(void* const* d_in, const int* in_sizes, int n_in,
                              void* d_out, int out_size, void* d_ws, size_t ws_size,
                              hipStream_t stream) {
    const float* x     = (const float*)d_in[0];
    const float* Wt    = (const float*)d_in[1];
    const float* Wp    = (const float*)d_in[2];
    const float* Wg    = (const float*)d_in[3];
    const float* W1    = (const float*)d_in[4];
    const float* W2    = (const float*)d_in[5];
    const float* gamma = (const float*)d_in[6];
    const float* beta  = (const float*)d_in[7];

    char* p = (char*)d_ws;
    auto alloc = [&](size_t bytes) { char* r = p; p += (bytes + 255) & ~(size_t)255; return r; };
    float*          out_sm = (float*)         alloc((size_t)Bc * Nc * Cc * 4);
    unsigned short* outh   = (unsigned short*)alloc((size_t)Bc * Nc * Cc * 2);
    unsigned short* U_sm   = (unsigned short*)alloc((size_t)Bc * Nc * 256 * 2);
    unsigned short* U_cm   = (unsigned short*)alloc((size_t)Bc * 256 * Nc * 2);
    unsigned short* agg    = (unsigned short*)alloc((size_t)Bc * Nc * 256 * 2);  // [ag | g]
    unsigned short* g_cmd  = (unsigned short*)alloc((size_t)Bc * Pc * Nc * 2);
    unsigned short* o_sm   = (unsigned short*)alloc((size_t)Bc * Nc * Cc * 2);
    float*          Cpart  = (float*)         alloc((size_t)KSn * Bc * Pc * Cc * 4);
    unsigned short* MstT   = (unsigned short*)alloc((size_t)Bc * Pc * Cc * 2);
    unsigned short* Wcomb  = (unsigned short*)alloc((size_t)Cc * Cc * 2);
    unsigned short* Wgh    = (unsigned short*)alloc((size_t)Sc * Pc * Cc * 2);
    unsigned short* Wcat   = (unsigned short*)alloc((size_t)Sc * Cc * 256 * 2);
    float*          rp     = (float*)         alloc((size_t)Bc * 49 * 256 * 4);
    float*          dinv   = (float*)         alloc((size_t)Bc * Nc * 4);
    float*          ps     = (float*)         alloc((size_t)196 * 256 * 4);
    float*          ps2    = (float*)         alloc((size_t)196 * 256 * 4);
    float*          scale  = (float*)         alloc(256 * 4);
    float*          shiftb = (float*)         alloc(256 * 4);

    const long NC256 = (long)Nc * 256;
    dim3 blk(256);

    cvtw_k<<<544, blk, 0, stream>>>(Wt, Wp, Wg, W1, W2, Wcomb, Wgh, Wcat);
    xpin_k<<<dim3(49, 4, Bc), blk, 0, stream>>>(x, out_sm, outh);

    // U = relu([Wt;Wp] @ x): spatial-major + column-major + column partial sums
    mgemm<1, 1, false, 1, false><<<dim3(2, 49, Bc), blk, 0, stream>>>(
        outh, 256, NC256, Wcomb, 256, 0,
        U_sm, 256, NC256, 0, U_cm, (long)256 * Nc, rp, nullptr, 256, 0, nullptr);

    dinv_k<<<dim3(13, Bc), blk, 0, stream>>>(U_sm, rp, dinv);

    for (int s = 0; s < Sc; ++s) {
        // g = Wg[s] @ out -> agg cols [128:256); g_cmd[p][i] = g*dinv (chan-major)
        mgemm<0, 2, false, 0, false><<<dim3(1, 49, Bc), blk, 0, stream>>>(
            outh, 256, NC256, Wgh + (size_t)s * Pc * Cc, 256, 0,
            agg + 128, 256, NC256, 0, g_cmd, (long)Pc * Nc, nullptr, nullptr,
            256, 0, dinv);
        // Cpart[ks][p][q] = partial_i g_cmd[p][i] * U_cm[q][i]   (f32 partials)
        mgemm<0, 0, true, 0, true><<<dim3(2, 2, KSn * Bc), blk, 0, stream>>>(
            g_cmd, Nc, (long)Pc * Nc, U_cm, Nc, (long)256 * Nc,
            (unsigned short*)Cpart, 256, (long)Pc * Cc, (long)Bc * Pc * Cc,
            nullptr, 0, nullptr, nullptr, Nc, KCH, nullptr);
        redmst_k<<<64, blk, 0, stream>>>(Cpart, MstT);
        // ag[n][p'] = 0.5*dinv[n] * sum_q U_sm[n][q] * MstT[p'][q] -> agg [0:128)
        mgemm<2, 0, false, 0, false><<<dim3(1, 49, Bc), blk, 0, stream>>>(
            U_sm, 256, NC256, MstT, 256, (long)Pc * Cc,
            agg, 256, NC256, 0, nullptr, 0, nullptr, nullptr, 256, 0, dinv);
        // o = Wcat[s] @ [ag; g]  + fused BN partial stats
        mgemm<0, 0, false, 2, false><<<dim3(2, 49, Bc), blk, 0, stream>>>(
            agg, 256, NC256, Wcat + (size_t)s * Cc * 256, 256, 0,
            o_sm, 256, NC256, 0, nullptr, 0, ps, ps2, 256, 0, nullptr);
        bnfin_k<<<16, blk, 0, stream>>>(ps, ps2, gamma + s * Cc, beta + s * Cc,
                                        scale, shiftb);
        bnapp_k<<<1568, blk, 0, stream>>>(o_sm, scale, shiftb, out_sm, outh);
    }

    xpout_k<<<dim3(49, 4, Bc), blk, 0, stream>>>(out_sm, (float*)d_out);
}

// Round 5
// 264.949 us; speedup vs baseline: 2.7045x; 1.0569x over previous
//
#include <hip/hip_runtime.h>

namespace {

constexpr int Bc = 4;
constexpr int Cc = 256;
constexpr int Pc = 128;
constexpr int NcT = 3136;  // true spatial size 56*56
constexpr int Np = 3200;   // padded to 25*128
constexpr int Sc = 5;
constexpr int KSn = 5;     // split-K chunks for abt (3200 = 5*640)
constexpr int KCH = 640;
constexpr float EPSc = 1e-5f;

typedef __attribute__((ext_vector_type(8))) short bf16x8;
typedef __attribute__((ext_vector_type(4))) float f32x4;
typedef __attribute__((ext_vector_type(8))) unsigned short u16x8;
typedef __attribute__((ext_vector_type(4))) unsigned short u16x4;

__device__ inline float bf2f(unsigned short u) {
    return __uint_as_float(((unsigned)u) << 16);
}
__device__ inline unsigned short f2bf(float f) {
    unsigned u = __float_as_uint(f);
    return (unsigned short)((u + 0x7FFFu + ((u >> 16) & 1u)) >> 16);
}

// ---------------------------------------------------------------------------
// MFMA GEMM: D[m][n] = sum_k A[m][k] * B[n][k]   (both operands K-contiguous)
// Tile MT(m) x 128(n); MT=128: 4 waves 2x2 (each 64x64, 8 ds_read / 16 MFMA
// per K32); MT=64: 4 waves 1x4 (each 64x32). K-step 64, double-buffered LDS
// via global_load_lds(16B) with granule swizzle phys = g ^ (row&7).
// EPI:    0 none, 1 relu, 2 scale rows by 0.5*dinv[b][m0+row]
// CMOUT:  0 none, 1 plain column-major copy, 2 column-major scaled by dinv[m]
// SPLITK: z = ks*Bc+b, k range [ks*kchunk,+kchunk), out offset ks*smSlice
// BNSTAT: 0 none, 1 column sums -> ps, 2 column sums+sumsq -> ps,ps2
// F32OUT: write f32 output (outSM reinterpreted as float*)
// FUSEBN: A operand computed on the fly = resid + BN(oin); resid updated.
// ---------------------------------------------------------------------------
template <int MT, int EPI, int CMOUT, bool SPLITK, int BNSTAT, bool F32OUT,
          bool FUSEBN>
__global__ __launch_bounds__(256) void mgemm(
    const unsigned short* __restrict__ A, int lda, long aB,
    const unsigned short* __restrict__ Bw, int ldb, long bB,
    unsigned short* __restrict__ outSM, int ldsm, long smB, long smSlice,
    unsigned short* __restrict__ outCM, long cmB,
    float* __restrict__ ps, float* __restrict__ ps2,
    int K, int kchunk, const float* __restrict__ dinv,
    const unsigned short* __restrict__ oin, const float* __restrict__ bnsc,
    const float* __restrict__ bnsh, float* __restrict__ resid)
{
    constexpr int TBA = MT * 64 * 2;
    constexpr int TBB = 128 * 64 * 2;
    constexpr int BUF = TBA + TBB;
    constexpr int OTB = MT * 132 * 4;
    constexpr int LDSZ = (2 * BUF > OTB + 2048) ? 2 * BUF : (OTB + 2048);
    __shared__ __align__(16) char lds[LDSZ];

    int b, kstart, kend;
    long smOff;
    if (SPLITK) {
        b = blockIdx.z & 3;
        int ks = blockIdx.z >> 2;
        kstart = ks * kchunk;
        kend = kstart + kchunk;
        smOff = (long)ks * smSlice;
    } else {
        b = blockIdx.z; kstart = 0; kend = K; smOff = 0;
    }
    const int n0 = blockIdx.x * 128;
    const int m0 = blockIdx.y * MT;
    const int tid = threadIdx.x;
    const int w = tid >> 6, l = tid & 63;

    const unsigned short* Ab = A + (size_t)b * aB + (size_t)m0 * lda;
    const unsigned short* Bb = Bw + (size_t)b * bB + (size_t)n0 * ldb;

    const int srow8 = tid >> 3;                 // 0..31
    const int sgran = tid & 7;
    const int sswz = (sgran ^ (srow8 & 7)) * 8; // swizzled source granule
    constexpr int AR = MT / 32;                 // A staging rounds

    constexpr int WC = (MT == 128) ? 2 : 4;     // waves along n
    constexpr int NB = 128 / WC / 16;           // B frags per wave (4 / 2)
    const int wr = w / WC, wc = w % WC;

    f32x4 acc[4][NB] = {};
    float fup[AR][8];

    auto stageA = [&](int buf, int k0) {
        char* base = lds + buf * BUF;
#pragma unroll
        for (int j = 0; j < AR; ++j)
            __builtin_amdgcn_global_load_lds(
                (const __attribute__((address_space(1))) void*)
                    (Ab + (size_t)(j * 32 + srow8) * lda + k0 + sswz),
                (__attribute__((address_space(3))) void*)(base + j * 4096 + tid * 16),
                16, 0, 0);
    };
    auto stageB = [&](int buf, int k0) {
        char* base = lds + buf * BUF + TBA;
#pragma unroll
        for (int j = 0; j < 4; ++j)
            __builtin_amdgcn_global_load_lds(
                (const __attribute__((address_space(1))) void*)
                    (Bb + (size_t)(j * 32 + srow8) * ldb + k0 + sswz),
                (__attribute__((address_space(3))) void*)(base + j * 4096 + tid * 16),
                16, 0, 0);
    };
    // FUSEBN: compute updated residual rows (f32 store) into fup registers
    auto fbLoad = [&](int k0) {
        const float* scp = bnsc + k0 + sgran * 8;
        const float* shp = bnsh + k0 + sgran * 8;
        float4 s0 = *(const float4*)scp, s1 = *(const float4*)(scp + 4);
        float4 h0 = *(const float4*)shp, h1 = *(const float4*)(shp + 4);
#pragma unroll
        for (int j = 0; j < AR; ++j) {
            int row = j * 32 + srow8;
            int n = m0 + row;
            size_t off = ((size_t)b * Np + n) * 256 + k0 + sgran * 8;
            if (n < NcT) {
                u16x8 ov = *(const u16x8*)(oin + off);
                float4 r0 = *(const float4*)(resid + off);
                float4 r1 = *(const float4*)(resid + off + 4);
                fup[j][0] = r0.x + fmaf(bf2f(ov[0]), s0.x, h0.x);
                fup[j][1] = r0.y + fmaf(bf2f(ov[1]), s0.y, h0.y);
                fup[j][2] = r0.z + fmaf(bf2f(ov[2]), s0.z, h0.z);
                fup[j][3] = r0.w + fmaf(bf2f(ov[3]), s0.w, h0.w);
                fup[j][4] = r1.x + fmaf(bf2f(ov[4]), s1.x, h1.x);
                fup[j][5] = r1.y + fmaf(bf2f(ov[5]), s1.y, h1.y);
                fup[j][6] = r1.z + fmaf(bf2f(ov[6]), s1.z, h1.z);
                fup[j][7] = r1.w + fmaf(bf2f(ov[7]), s1.w, h1.w);
            } else {
#pragma unroll
                for (int i = 0; i < 8; ++i) fup[j][i] = 0.f;
            }
            float4 w0, w1;
            w0.x = fup[j][0]; w0.y = fup[j][1]; w0.z = fup[j][2]; w0.w = fup[j][3];
            w1.x = fup[j][4]; w1.y = fup[j][5]; w1.z = fup[j][6]; w1.w = fup[j][7];
            *(float4*)(resid + off) = w0;
            *(float4*)(resid + off + 4) = w1;
        }
    };
    auto fbWrite = [&](int buf) {
        char* base = lds + buf * BUF;
#pragma unroll
        for (int j = 0; j < AR; ++j) {
            int row = j * 32 + srow8;
            u16x8 hv;
#pragma unroll
            for (int i = 0; i < 8; ++i) hv[i] = f2bf(fup[j][i]);
            *(u16x8*)(base + row * 128 + ((sgran ^ (row & 7)) << 4)) = hv;
        }
    };

    auto compute = [&](int buf) {
        const char* base = lds + buf * BUF;
        const int lo = l & 15, gq = l >> 4;
#pragma unroll
        for (int kh = 0; kh < 2; ++kh) {
            const int lg = kh * 4 + gq;
            bf16x8 bf[NB];
#pragma unroll
            for (int c = 0; c < NB; ++c) {
                int brow = wc * (16 * NB) + c * 16 + lo;
                bf[c] = *(const bf16x8*)(base + TBA + brow * 128 +
                                         ((lg ^ (brow & 7)) << 4));
            }
#pragma unroll
            for (int r = 0; r < 4; ++r) {
                int arow = wr * 64 + r * 16 + lo;
                bf16x8 af = *(const bf16x8*)(base + arow * 128 +
                                             ((lg ^ (arow & 7)) << 4));
#pragma unroll
                for (int c = 0; c < NB; ++c)
                    acc[r][c] = __builtin_amdgcn_mfma_f32_16x16x32_bf16(
                        af, bf[c], acc[r][c], 0, 0, 0);
            }
        }
    };

    const int nst = (kend - kstart) >> 6;
    if constexpr (FUSEBN) {
        fbLoad(kstart);
        fbWrite(0);
        stageB(0, kstart);
        __syncthreads();
        for (int s = 0; s < nst; ++s) {
            if (s + 1 < nst) {
                fbLoad(kstart + ((s + 1) << 6));
                stageB((s + 1) & 1, kstart + ((s + 1) << 6));
            }
            compute(s & 1);
            if (s + 1 < nst) fbWrite((s + 1) & 1);
            __syncthreads();
        }
    } else {
        stageA(0, kstart);
        stageB(0, kstart);
        __syncthreads();
        for (int s = 0; s < nst; ++s) {
            if (s + 1 < nst) {
                stageA((s + 1) & 1, kstart + ((s + 1) << 6));
                stageB((s + 1) & 1, kstart + ((s + 1) << 6));
            }
            compute(s & 1);
            __syncthreads();
        }
    }

    // stage accumulators to LDS f32 [MT][132]
    float* ot = (float*)lds;
    {
        const int lo = l & 15, gq = l >> 4;
#pragma unroll
        for (int r = 0; r < 4; ++r)
#pragma unroll
            for (int c = 0; c < NB; ++c)
#pragma unroll
                for (int j = 0; j < 4; ++j) {
                    float v = acc[r][c][j];
                    if (EPI == 1) v = fmaxf(v, 0.f);
                    ot[(wr * 64 + r * 16 + gq * 4 + j) * 132 +
                       wc * (16 * NB) + c * 16 + lo] = v;
                }
    }
    __syncthreads();

    {   // row-major store
        constexpr int TPR = 256 / MT;           // threads per row
        const int r = tid / TPR;
        const int c0 = (tid % TPR) * (MT / 2);
        if (F32OUT) {
            float* dst = (float*)outSM + (size_t)b * smB + smOff +
                         (size_t)(m0 + r) * ldsm + n0 + c0;
#pragma unroll
            for (int k = 0; k < MT / 8; ++k) {
                float4 v;
                v.x = ot[r * 132 + c0 + 4 * k + 0];
                v.y = ot[r * 132 + c0 + 4 * k + 1];
                v.z = ot[r * 132 + c0 + 4 * k + 2];
                v.w = ot[r * 132 + c0 + 4 * k + 3];
                *(float4*)(dst + 4 * k) = v;
            }
        } else {
            float sc = 1.f;
            if (EPI == 2) sc = 0.5f * dinv[(size_t)b * Np + m0 + r];
            unsigned short* dst = outSM + (size_t)b * smB + smOff +
                                  (size_t)(m0 + r) * ldsm + n0 + c0;
#pragma unroll
            for (int k = 0; k < MT / 16; ++k) {
                u16x8 o;
#pragma unroll
                for (int j = 0; j < 8; ++j) {
                    float v = ot[r * 132 + c0 + 8 * k + j];
                    if (EPI == 2) v *= sc;
                    o[j] = f2bf(v);
                }
                *(u16x8*)(dst + 8 * k) = o;
            }
        }
    }

    if (CMOUT) {   // column-major store
        const int c = tid >> 1, r0 = (tid & 1) * (MT / 2);
        const float* dv = dinv + (size_t)b * Np + m0 + r0;
        unsigned short* dst = outCM + (size_t)b * cmB + (size_t)(n0 + c) * Np +
                              m0 + r0;
#pragma unroll
        for (int k = 0; k < MT / 16; ++k) {
            u16x8 o;
#pragma unroll
            for (int j = 0; j < 8; ++j) {
                float v = ot[(r0 + 8 * k + j) * 132 + c];
                if (CMOUT == 2) v *= dv[8 * k + j];
                o[j] = f2bf(v);
            }
            *(u16x8*)(dst + 8 * k) = o;
        }
    }

    if (BNSTAT) {
        float* p1 = (float*)(lds + OTB);
        float* p2 = p1 + 256;
        const int col = tid & 127, half = tid >> 7;
        float s = 0.f, s2 = 0.f;
#pragma unroll
        for (int i = 0; i < MT / 2; ++i) {
            float v = ot[(half * (MT / 2) + i) * 132 + col];
            s += v;
            if (BNSTAT == 2) s2 = fmaf(v, v, s2);
        }
        p1[half * 128 + col] = s;
        if (BNSTAT == 2) p2[half * 128 + col] = s2;
        __syncthreads();
        if (tid < 128) {
            float a = p1[tid] + p1[128 + tid];
            size_t slot = ((size_t)b * gridDim.y + blockIdx.y) * 256 + n0 + tid;
            ps[slot] = a;
            if (BNSTAT == 2) ps2[slot] = p2[tid] + p2[128 + tid];
        }
    }
}

// ---------------------------------------------------------------------------
// weights f32 -> bf16; Wt+Wp -> Wcomb[256][256]; W1,W2 interleaved -> Wcat
// ---------------------------------------------------------------------------
__global__ __launch_bounds__(256) void cvtw_k(
    const float* __restrict__ Wt, const float* __restrict__ Wp,
    const float* __restrict__ Wg, const float* __restrict__ W1,
    const float* __restrict__ W2,
    unsigned short* __restrict__ Wcomb, unsigned short* __restrict__ Wgh,
    unsigned short* __restrict__ Wcat)
{
    size_t e = ((size_t)blockIdx.x * 256 + threadIdx.x) * 4;
    const float* src; unsigned short* dst;
    if (e < 32768)      { src = Wt + e;           dst = Wcomb + e; }
    else if (e < 65536) { src = Wp + (e - 32768); dst = Wcomb + e; }
    else if (e < 65536 + 163840) {
        size_t o = e - 65536; src = Wg + o; dst = Wgh + o;
    } else if (e < 65536 + 2 * 163840) {
        size_t o = e - 65536 - 163840; src = W1 + o;
        dst = Wcat + ((o >> 7) << 8) + (o & 127);
    } else {
        size_t o = e - 65536 - 327680; src = W2 + o;
        dst = Wcat + ((o >> 7) << 8) + 128 + (o & 127);
    }
    float4 v = *(const float4*)src;
    u16x4 t;
    t[0] = f2bf(v.x); t[1] = f2bf(v.y); t[2] = f2bf(v.z); t[3] = f2bf(v.w);
    *(u16x4*)dst = t;
}

// x[b][c][n] f32 -> out_sm[b][n][c] f32 + outh bf16 (rows >= NcT zeroed)
__global__ __launch_bounds__(256) void xpin_k(
    const float* __restrict__ x, float* __restrict__ out_sm,
    unsigned short* __restrict__ outh)
{
    __shared__ float tb[64][65];
    int b = blockIdx.z, c0 = blockIdx.y * 64, n0 = blockIdx.x * 64;
    int t = threadIdx.x;
    const bool pad = (n0 >= NcT);
    if (!pad) {
        int ci = t >> 2, nb = (t & 3) * 16;
        const float* src = x + ((size_t)b * Cc + c0 + ci) * NcT + n0 + nb;
#pragma unroll
        for (int k = 0; k < 4; ++k) {
            float4 v = *(const float4*)(src + 4 * k);
            tb[ci][nb + 4 * k + 0] = v.x; tb[ci][nb + 4 * k + 1] = v.y;
            tb[ci][nb + 4 * k + 2] = v.z; tb[ci][nb + 4 * k + 3] = v.w;
        }
    }
    __syncthreads();
    int r = t >> 2, cb = (t & 3) * 16;
    size_t off = ((size_t)b * Np + n0 + r) * 256 + c0 + cb;
    float vv[16];
#pragma unroll
    for (int j = 0; j < 16; ++j) vv[j] = pad ? 0.f : tb[cb + j][r];
    float* dst = out_sm + off;
#pragma unroll
    for (int k = 0; k < 4; ++k) {
        float4 v; v.x = vv[4*k]; v.y = vv[4*k+1]; v.z = vv[4*k+2]; v.w = vv[4*k+3];
        *(float4*)(dst + 4 * k) = v;
    }
    u16x8 h1, h2;
#pragma unroll
    for (int j = 0; j < 8; ++j) { h1[j] = f2bf(vv[j]); h2[j] = f2bf(vv[8 + j]); }
    unsigned short* dh = outh + off;
    *(u16x8*)dh = h1;
    *(u16x8*)(dh + 8) = h2;
}

// d_out[b][c][n] = transpose(out_sm + BN(o))   (final stage fused)
__global__ __launch_bounds__(256) void xpoutbn_k(
    const float* __restrict__ out_sm, const unsigned short* __restrict__ oin,
    const float* __restrict__ scale, const float* __restrict__ shift,
    float* __restrict__ outp)
{
    __shared__ float tb[64][65];
    __shared__ float lsc[64], lsh[64];
    int b = blockIdx.z, c0 = blockIdx.y * 64, n0 = blockIdx.x * 64;
    int t = threadIdx.x;
    if (t < 64) { lsc[t] = scale[c0 + t]; lsh[t] = shift[c0 + t]; }
    __syncthreads();
    {
        int r = t >> 2, cb = (t & 3) * 16;
        size_t off = ((size_t)b * Np + n0 + r) * 256 + c0 + cb;
#pragma unroll
        for (int k = 0; k < 2; ++k) {
            float4 a0 = *(const float4*)(out_sm + off + 8 * k);
            float4 a1 = *(const float4*)(out_sm + off + 8 * k + 4);
            u16x8 ov = *(const u16x8*)(oin + off + 8 * k);
            tb[r][cb + 8*k + 0] = a0.x + fmaf(bf2f(ov[0]), lsc[cb + 8*k + 0], lsh[cb + 8*k + 0]);
            tb[r][cb + 8*k + 1] = a0.y + fmaf(bf2f(ov[1]), lsc[cb + 8*k + 1], lsh[cb + 8*k + 1]);
            tb[r][cb + 8*k + 2] = a0.z + fmaf(bf2f(ov[2]), lsc[cb + 8*k + 2], lsh[cb + 8*k + 2]);
            tb[r][cb + 8*k + 3] = a0.w + fmaf(bf2f(ov[3]), lsc[cb + 8*k + 3], lsh[cb + 8*k + 3]);
            tb[r][cb + 8*k + 4] = a1.x + fmaf(bf2f(ov[4]), lsc[cb + 8*k + 4], lsh[cb + 8*k + 4]);
            tb[r][cb + 8*k + 5] = a1.y + fmaf(bf2f(ov[5]), lsc[cb + 8*k + 5], lsh[cb + 8*k + 5]);
            tb[r][cb + 8*k + 6] = a1.z + fmaf(bf2f(ov[6]), lsc[cb + 8*k + 6], lsh[cb + 8*k + 6]);
            tb[r][cb + 8*k + 7] = a1.w + fmaf(bf2f(ov[7]), lsc[cb + 8*k + 7], lsh[cb + 8*k + 7]);
        }
    }
    __syncthreads();
    {
        int c = t >> 2, rb = (t & 3) * 16;
        float vv[16];
#pragma unroll
        for (int j = 0; j < 16; ++j) vv[j] = tb[rb + j][c];
        float* dst = outp + ((size_t)b * Cc + c0 + c) * NcT + n0 + rb;
#pragma unroll
        for (int k = 0; k < 4; ++k) {
            float4 v; v.x = vv[4*k]; v.y = vv[4*k+1]; v.z = vv[4*k+2]; v.w = vv[4*k+3];
            *(float4*)(dst + 4 * k) = v;
        }
    }
}

// dinv[b][i] = d>0 ? rsqrt(d) : 0, d = 0.5 * sum_q U_sm[b][i][q] * rs[b][q^128]
__global__ __launch_bounds__(256) void dinv_k(
    const unsigned short* __restrict__ U, const float* __restrict__ rp,
    float* __restrict__ dinv)
{
    __shared__ float rsl[256];
    int b = blockIdx.y, tid = threadIdx.x;
    float s = 0.f;
    for (int j = 0; j < 25; ++j) s += rp[((size_t)b * 25 + j) * 256 + tid];
    rsl[tid ^ 128] = s;
    __syncthreads();
    int i = blockIdx.x * 256 + tid;
    if (i < Np) {
        const unsigned short* row = U + ((size_t)b * Np + i) * 256;
        float acc = 0.f;
        for (int q0 = 0; q0 < 256; q0 += 8) {
            u16x8 v = *(const u16x8*)(row + q0);
#pragma unroll
            for (int j = 0; j < 8; ++j) acc = fmaf(bf2f(v[j]), rsl[q0 + j], acc);
        }
        float d = 0.5f * acc;
        dinv[(size_t)b * Np + i] = d > 0.f ? rsqrtf(d) : 0.f;
    }
}

// MstT[b][p][q] = sum_ks Cpart_f32[ks][b][p][q^128]  -> bf16
__global__ __launch_bounds__(256) void redmst_k(
    const float* __restrict__ Cpart, unsigned short* __restrict__ MstT)
{
    int e8 = blockIdx.x * 256 + threadIdx.x;    // 16384 total
    int bp = e8 >> 5, qc = e8 & 31;
    size_t dstOff = ((size_t)bp * 32 + qc) * 8;
    size_t srcOff = ((size_t)bp * 32 + (qc ^ 16)) * 8;
    float4 s0 = {0.f, 0.f, 0.f, 0.f}, s1 = {0.f, 0.f, 0.f, 0.f};
    for (int ks = 0; ks < KSn; ++ks) {
        const float* base = Cpart + (size_t)ks * (Bc * Pc * Cc) + srcOff;
        float4 v0 = *(const float4*)base;
        float4 v1 = *(const float4*)(base + 4);
        s0.x += v0.x; s0.y += v0.y; s0.z += v0.z; s0.w += v0.w;
        s1.x += v1.x; s1.y += v1.y; s1.z += v1.z; s1.w += v1.w;
    }
    u16x8 o;
    o[0] = f2bf(s0.x); o[1] = f2bf(s0.y); o[2] = f2bf(s0.z); o[3] = f2bf(s0.w);
    o[4] = f2bf(s1.x); o[5] = f2bf(s1.y); o[6] = f2bf(s1.z); o[7] = f2bf(s1.w);
    *(u16x8*)(MstT + dstOff) = o;
}

// parallel BN finalize: 16 blocks x 16 channels; 100 partial groups
__global__ __launch_bounds__(256) void bnfin_k(
    const float* __restrict__ ps, const float* __restrict__ ps2,
    const float* __restrict__ gamma, const float* __restrict__ beta,
    float* __restrict__ scale, float* __restrict__ shift)
{
    __shared__ float l1[256], l2[256];
    int t = threadIdx.x;
    int c = blockIdx.x * 16 + (t & 15);
    int gl = t >> 4;
    float a = 0.f, a2 = 0.f;
    for (int g = gl; g < 100; g += 16) {
        a += ps[(size_t)g * 256 + c];
        a2 += ps2[(size_t)g * 256 + c];
    }
    l1[t] = a; l2[t] = a2;
    __syncthreads();
    if (gl == 0) {
#pragma unroll
        for (int j = 1; j < 16; ++j) {
            a += l1[j * 16 + (t & 15)];
            a2 += l2[j * 16 + (t & 15)];
        }
        const float inv = 1.f / (float)(Bc * NcT);
        float mean = a * inv;
        float var = a2 * inv - mean * mean;
        float sc = gamma[c] * rsqrtf(var + EPSc);
        scale[c] = sc;
        shift[c] = beta[c] - mean * sc;
    }
}

}  // namespace

extern "C" void kernel_launch(void* const* d_in, const int* in_sizes, int n_in,
                              void* d_out, int out_size, void* d_ws, size_t ws_size,
                              hipStream_t stream) {
    const float* x     = (const float*)d_in[0];
    const float* Wt    = (const float*)d_in[1];
    const float* Wp    = (const float*)d_in[2];
    const float* Wg    = (const float*)d_in[3];
    const float* W1    = (const float*)d_in[4];
    const float* W2    = (const float*)d_in[5];
    const float* gamma = (const float*)d_in[6];
    const float* beta  = (const float*)d_in[7];

    char* p = (char*)d_ws;
    auto alloc = [&](size_t bytes) { char* r = p; p += (bytes + 255) & ~(size_t)255; return r; };
    float*          out_sm = (float*)         alloc((size_t)Bc * Np * 256 * 4);
    unsigned short* outh   = (unsigned short*)alloc((size_t)Bc * Np * 256 * 2);
    unsigned short* U_sm   = (unsigned short*)alloc((size_t)Bc * Np * 256 * 2);
    unsigned short* U_cm   = (unsigned short*)alloc((size_t)Bc * 256 * Np * 2);
    unsigned short* agg    = (unsigned short*)alloc((size_t)Bc * Np * 256 * 2);  // [ag | g]
    unsigned short* g_cmd  = (unsigned short*)alloc((size_t)Bc * Pc * Np * 2);
    unsigned short* o_sm   = (unsigned short*)alloc((size_t)Bc * Np * 256 * 2);
    float*          Cpart  = (float*)         alloc((size_t)KSn * Bc * Pc * Cc * 4);
    unsigned short* MstT   = (unsigned short*)alloc((size_t)Bc * Pc * Cc * 2);
    unsigned short* Wcomb  = (unsigned short*)alloc((size_t)Cc * Cc * 2);
    unsigned short* Wgh    = (unsigned short*)alloc((size_t)Sc * Pc * Cc * 2);
    unsigned short* Wcat   = (unsigned short*)alloc((size_t)Sc * Cc * 256 * 2);
    float*          rp     = (float*)         alloc((size_t)100 * 256 * 4);
    float*          dinv   = (float*)         alloc((size_t)Bc * Np * 4);
    float*          ps     = (float*)         alloc((size_t)100 * 256 * 4);
    float*          ps2    = (float*)         alloc((size_t)100 * 256 * 4);
    float*          scale  = (float*)         alloc(256 * 4);
    float*          shiftb = (float*)         alloc(256 * 4);

    const long NpC = (long)Np * 256;
    dim3 blk(256);

    cvtw_k<<<544, blk, 0, stream>>>(Wt, Wp, Wg, W1, W2, Wcomb, Wgh, Wcat);
    xpin_k<<<dim3(50, 4, Bc), blk, 0, stream>>>(x, out_sm, outh);

    // U = relu([Wt;Wp] @ x): spatial-major + column-major + column partial sums
    mgemm<128, 1, 1, false, 1, false, false><<<dim3(2, 25, Bc), blk, 0, stream>>>(
        outh, 256, NpC, Wcomb, 256, 0,
        U_sm, 256, NpC, 0, U_cm, (long)256 * Np, rp, nullptr,
        256, 0, nullptr, nullptr, nullptr, nullptr, nullptr);

    dinv_k<<<dim3(13, Bc), blk, 0, stream>>>(U_sm, rp, dinv);

    for (int s = 0; s < Sc; ++s) {
        // g = Wg[s] @ out -> agg cols [128:256); g_cmd = g*dinv (chan-major)
        if (s == 0)
            mgemm<64, 0, 2, false, 0, false, false><<<dim3(1, 50, Bc), blk, 0, stream>>>(
                outh, 256, NpC, Wgh, 256, 0,
                agg + 128, 256, NpC, 0, g_cmd, (long)Pc * Np, nullptr, nullptr,
                256, 0, dinv, nullptr, nullptr, nullptr, nullptr);
        else
            mgemm<64, 0, 2, false, 0, false, true><<<dim3(1, 50, Bc), blk, 0, stream>>>(
                outh, 256, NpC, Wgh + (size_t)s * Pc * Cc, 256, 0,
                agg + 128, 256, NpC, 0, g_cmd, (long)Pc * Np, nullptr, nullptr,
                256, 0, dinv, o_sm, scale, shiftb, out_sm);
        // Cpart[ks][p][q] = partial_i g_cmd[p][i] * U_cm[q][i]   (f32 partials)
        mgemm<64, 0, 0, true, 0, true, false><<<dim3(2, 2, KSn * Bc), blk, 0, stream>>>(
            g_cmd, Np, (long)Pc * Np, U_cm, Np, (long)256 * Np,
            (unsigned short*)Cpart, 256, (long)Pc * Cc, (long)Bc * Pc * Cc,
            nullptr, 0, nullptr, nullptr, Np, KCH, nullptr,
            nullptr, nullptr, nullptr, nullptr);
        redmst_k<<<64, blk, 0, stream>>>(Cpart, MstT);
        // ag[n][p'] = 0.5*dinv[n] * sum_q U_sm[n][q] * MstT[p'][q] -> agg [0:128)
        mgemm<64, 2, 0, false, 0, false, false><<<dim3(1, 50, Bc), blk, 0, stream>>>(
            U_sm, 256, NpC, MstT, 256, (long)Pc * Cc,
            agg, 256, NpC, 0, nullptr, 0, nullptr, nullptr,
            256, 0, dinv, nullptr, nullptr, nullptr, nullptr);
        // o = Wcat[s] @ [ag; g]  + fused BN partial stats
        mgemm<128, 0, 0, false, 2, false, false><<<dim3(2, 25, Bc), blk, 0, stream>>>(
            agg, 256, NpC, Wcat + (size_t)s * Cc * 256, 256, 0,
            o_sm, 256, NpC, 0, nullptr, 0, ps, ps2,
            256, 0, nullptr, nullptr, nullptr, nullptr, nullptr);
        bnfin_k<<<16, blk, 0, stream>>>(ps, ps2, gamma + s * Cc, beta + s * Cc,
                                        scale, shiftb);
    }

    // final: d_out = transpose(out_sm + BN(o_sm))
    xpoutbn_k<<<dim3(49, 4, Bc), blk, 0, stream>>>(out_sm, o_sm, scale, shiftb,
                                                   (float*)d_out);
}